// Round 13
// baseline (1136.970 us; speedup 1.0000x reference)
//
#include <hip/hip_runtime.h>
#include <hip/hip_bf16.h>
#include <math.h>

static constexpr int Bsz  = 1024;
static constexpr int Lseq = 32;
static constexpr int Dm   = 256;
static constexpr int NROW = Bsz * Lseq;   // 32768

typedef __attribute__((ext_vector_type(8))) short bf16x8;
typedef __attribute__((ext_vector_type(4))) float f32x4;

__device__ __forceinline__ float sigm_f(float x) {
    return 1.0f / (1.0f + __expf(-x));
}
__device__ __forceinline__ float gelu_f(float x) {
    const float u = x * (0.7978845608028654f + 0.0356774081f * x * x);
    return x * sigm_f(2.0f * u);
}
__device__ __forceinline__ float b2f(ushort u) {
    union { float f; uint v; } t; t.v = ((uint)u) << 16; return t.f;
}
__device__ __forceinline__ ushort f2b(float f) {
    union { float f; uint v; } t; t.f = f;
    const uint lsb = (t.v >> 16) & 1u;
    t.v += 0x7fffu + lsb;
    return (ushort)(t.v >> 16);
}

#define GLDS(gp, lp) __builtin_amdgcn_global_load_lds( \
    (const __attribute__((address_space(1))) void*)(gp), \
    (__attribute__((address_space(3))) void*)(lp), 16, 0, 0)

// BK=64 staging scheme: chunk = 8 rows x 64 cols bf16 (1 KB);
// lane l -> row l>>3, 16B-slot l&7; stored slot = s ^ (row & 7).
// LDS ushort idx (row r, k-slot s): r*64 + ((s ^ (r&7)) << 3).

// ---------------------------------------------------------------------------
// bf16 MFMA GEMM, 128x128 tile, BK=64, 256 threads (proven version).
// ACT: 0 none, 1 sigm, 2 gelu. OMAP: 1 = scan-H remap (stride-64 Hpad) with
// triangular K-limit (T block-lower-triangular: k >= m0+128 contributes 0).
// DUAL: 1 gateIn: Cb = sigm(A@W+b1)*(A@W2+b2); 2: Cb=A@W+b1, Cb2=A@W2+b2.
// XCD-aware bijective block swizzle + LDS-repacked coalesced bf16 epilogue.
// ---------------------------------------------------------------------------
template<int ACT, bool OUTBF, int OMAP, int DUAL>
__global__ __launch_bounds__(256)
void mgemm(const ushort* __restrict__ X, const ushort* __restrict__ W,
           const ushort* __restrict__ W2,
           const float* __restrict__ b1, const float* __restrict__ b2,
           float* __restrict__ Cf, ushort* __restrict__ Cb,
           ushort* __restrict__ Cb2, int K, int M)
{
    __shared__ ushort As[8192];                 // 128 x 64
    __shared__ ushort Bs[8192];
    __shared__ ushort Bs2[DUAL ? 8192 : 8];
    const int tid = threadIdx.x;
    const int w = tid >> 6, l = tid & 63;

    int f = blockIdx.y * gridDim.x + blockIdx.x;
    const int nwg = gridDim.x * gridDim.y;
    if ((nwg & 7) == 0) f = (f & 7) * (nwg >> 3) + (f >> 3);
    const int n0 = (f / gridDim.x) << 7;
    const int m0 = (f % gridDim.x) << 7;

    const int ric = l >> 3;          // row in chunk 0..7
    const int sl  = l & 7;           // 16B slot 0..7
    const ushort* gAp[4]; const ushort* gBp[4]; const ushort* gCp[DUAL ? 4 : 1];
    ushort* lAp[4]; ushort* lBp[4]; ushort* lCp[DUAL ? 4 : 1];
    #pragma unroll
    for (int c = 0; c < 4; ++c) {
        const int r = ((w << 2) + c) * 8 + ric;
        const int eo = (sl ^ (r & 7)) << 3;
        gAp[c] = X + (size_t)(n0 + r) * K + eo;
        gBp[c] = W + (size_t)(m0 + r) * K + eo;
        lAp[c] = As + (((w << 2) + c) << 9);
        lBp[c] = Bs + (((w << 2) + c) << 9);
        if constexpr (DUAL) {
            gCp[c] = W2 + (size_t)(m0 + r) * K + eo;
            lCp[c] = Bs2 + (((w << 2) + c) << 9);
        }
    }

    const int wr = (w >> 1) & 1, wc = w & 1;
    const int cl = l & 15, kg = l >> 4;
    int aoff[2][4], boff[2][4];
    #pragma unroll
    for (int sub = 0; sub < 2; ++sub) {
        const int s = sub * 4 + kg;
        #pragma unroll
        for (int m = 0; m < 4; ++m) {
            const int r = wr * 64 + m * 16 + cl;
            aoff[sub][m] = r * 64 + ((s ^ (r & 7)) << 3);
        }
        #pragma unroll
        for (int n = 0; n < 4; ++n) {
            const int r = wc * 64 + n * 16 + cl;
            boff[sub][n] = r * 64 + ((s ^ (r & 7)) << 3);
        }
    }

    f32x4 acc[4][4];
    f32x4 acc2[DUAL ? 4 : 1][DUAL ? 4 : 1];
    #pragma unroll
    for (int m = 0; m < 4; ++m)
        #pragma unroll
        for (int n = 0; n < 4; ++n) {
            acc[m][n] = (f32x4){0.f, 0.f, 0.f, 0.f};
            if constexpr (DUAL) acc2[m][n] = (f32x4){0.f, 0.f, 0.f, 0.f};
        }

    // Triangular skip for the scan-H GEMM: tile needs only k < m0+128.
    const int Klim = (OMAP == 1) ? (m0 + 128 < K ? m0 + 128 : K) : K;
    for (int kc = 0; kc < Klim; kc += 64) {
        #pragma unroll
        for (int c = 0; c < 4; ++c) {
            GLDS(gAp[c], lAp[c]); gAp[c] += 64;
            GLDS(gBp[c], lBp[c]); gBp[c] += 64;
            if constexpr (DUAL) { GLDS(gCp[c], lCp[c]); gCp[c] += 64; }
        }
        __syncthreads();
        #pragma unroll
        for (int sub = 0; sub < 2; ++sub) {
            bf16x8 av[4], bv[4];
            #pragma unroll
            for (int m = 0; m < 4; ++m) av[m] = *(const bf16x8*)(As + aoff[sub][m]);
            #pragma unroll
            for (int n = 0; n < 4; ++n) bv[n] = *(const bf16x8*)(Bs + boff[sub][n]);
            #pragma unroll
            for (int m = 0; m < 4; ++m)
                #pragma unroll
                for (int n = 0; n < 4; ++n)
                    acc[m][n] = __builtin_amdgcn_mfma_f32_16x16x32_bf16(
                        av[m], bv[n], acc[m][n], 0, 0, 0);
            if constexpr (DUAL) {
                bf16x8 cv[4];
                #pragma unroll
                for (int n = 0; n < 4; ++n) cv[n] = *(const bf16x8*)(Bs2 + boff[sub][n]);
                #pragma unroll
                for (int m = 0; m < 4; ++m)
                    #pragma unroll
                    for (int n = 0; n < 4; ++n)
                        acc2[m][n] = __builtin_amdgcn_mfma_f32_16x16x32_bf16(
                            av[m], cv[n], acc2[m][n], 0, 0, 0);
            }
        }
        __syncthreads();
    }

    const int colb = m0 + wc * 64 + cl;
    const int rowb = n0 + wr * 64 + (kg << 2);
    float biasA[4], biasB[4];
    #pragma unroll
    for (int n = 0; n < 4; ++n) {
        biasA[n] = (b1 != nullptr) ? b1[colb + n * 16] : 0.0f;
        if constexpr (DUAL) biasB[n] = b2[colb + n * 16];
    }

    if constexpr (OUTBF || DUAL != 0) {
        ushort* Rw = (w == 0) ? As : (w == 1) ? As + 4096
                   : (w == 2) ? Bs : Bs + 4096;
        const int rr = l >> 3, rc8 = (l & 7) << 3;
        const int nout = (DUAL == 2) ? 2 : 1;
        for (int which = 0; which < nout; ++which) {
            #pragma unroll
            for (int m = 0; m < 4; ++m)
                #pragma unroll
                for (int j = 0; j < 4; ++j) {
                    const int lrow = m * 16 + (kg << 2) + j;
                    #pragma unroll
                    for (int n = 0; n < 4; ++n) {
                        float v;
                        if (which == 0) {
                            v = acc[m][n][j] + biasA[n];
                            if constexpr (DUAL == 1)
                                v = sigm_f(v) * (acc2[m][n][j] + biasB[n]);
                            else if (ACT == 1) v = sigm_f(v);
                            else if (ACT == 2) v = gelu_f(v);
                        } else {
                            v = acc2[m][n][j] + biasB[n];
                        }
                        const int lcol = (n << 4) + cl;
                        Rw[lrow * 64 + (lcol ^ (((lrow >> 1) & 7) << 3))] = f2b(v);
                    }
                }
            ushort* dst = (which == 0) ? Cb : Cb2;
            #pragma unroll
            for (int p = 0; p < 8; ++p) {
                const int lrow = (p << 3) + rr;
                const bf16x8 v8 = *(const bf16x8*)(
                    Rw + lrow * 64 + (rc8 ^ (((lrow >> 1) & 7) << 3)));
                const size_t grow = (size_t)(n0 + wr * 64 + lrow);
                const int gcol = m0 + wc * 64 + rc8;
                size_t idx;
                if (OMAP == 1) idx = grow * 2048 + ((size_t)(gcol >> 4) << 6) + (gcol & 15);
                else           idx = grow * (size_t)M + gcol;
                *(bf16x8*)(dst + idx) = v8;
            }
        }
    } else {
        #pragma unroll
        for (int m = 0; m < 4; ++m)
            #pragma unroll
            for (int j = 0; j < 4; ++j) {
                const size_t row = (size_t)(rowb + m * 16 + j);
                #pragma unroll
                for (int n = 0; n < 4; ++n) {
                    float v = acc[m][n][j] + biasA[n];
                    if (ACT == 1) v = sigm_f(v);
                    else if (ACT == 2) v = gelu_f(v);
                    Cf[row * (size_t)M + colb + n * 16] = v;
                }
            }
    }
}

// ---------------------------------------------------------------------------
// f1 GEMM: wide tile 128 rows x 256 cols, BK=64, K=256, M=1024 fixed.
// S1 = gelu(S0 @ W1^T + b1). 64 MFMA per barrier pair (2x the 128^2 tile).
// Grid (4, 256); 256 threads; 4 waves = 2 rowg x 2 colg, each 64r x 128c.
// ---------------------------------------------------------------------------
__global__ __launch_bounds__(256, 2)
void f1_gemm(const ushort* __restrict__ X, const ushort* __restrict__ W,
             const float* __restrict__ b1, ushort* __restrict__ Cb)
{
    __shared__ ushort As[8192];     // 128 x 64 (16 KB)
    __shared__ ushort Bs[16384];    // 256 x 64 (32 KB)
    const int tid = threadIdx.x;
    const int w = tid >> 6, l = tid & 63;

    int f = blockIdx.y * 4 + blockIdx.x;       // nwg = 1024
    f = (f & 7) * 128 + (f >> 3);              // XCD swizzle
    const int n0 = (f >> 2) << 7;
    const int m0 = (f & 3) << 8;

    const int ric = l >> 3, sl = l & 7;
    const ushort* gAp[4]; ushort* lAp[4];
    const ushort* gBp[8]; ushort* lBp[8];
    #pragma unroll
    for (int c = 0; c < 4; ++c) {
        const int r = ((w << 2) + c) * 8 + ric;            // 0..127
        gAp[c] = X + (size_t)(n0 + r) * 256 + ((sl ^ (r & 7)) << 3);
        lAp[c] = As + (((w << 2) + c) << 9);
    }
    #pragma unroll
    for (int c = 0; c < 8; ++c) {
        const int r = ((w << 3) + c) * 8 + ric;            // 0..255
        gBp[c] = W + (size_t)(m0 + r) * 256 + ((sl ^ (r & 7)) << 3);
        lBp[c] = Bs + (((w << 3) + c) << 9);
    }

    const int wr = (w >> 1) & 1, wc = w & 1;
    const int cl = l & 15, kg = l >> 4;
    int aoff[2][4], boff[2][8];
    #pragma unroll
    for (int sub = 0; sub < 2; ++sub) {
        const int s = sub * 4 + kg;
        #pragma unroll
        for (int m = 0; m < 4; ++m) {
            const int r = wr * 64 + m * 16 + cl;
            aoff[sub][m] = r * 64 + ((s ^ (r & 7)) << 3);
        }
        #pragma unroll
        for (int n = 0; n < 8; ++n) {
            const int r = wc * 128 + n * 16 + cl;
            boff[sub][n] = r * 64 + ((s ^ (r & 7)) << 3);
        }
    }

    f32x4 acc[4][8];
    #pragma unroll
    for (int m = 0; m < 4; ++m)
        #pragma unroll
        for (int n = 0; n < 8; ++n) acc[m][n] = (f32x4){0.f, 0.f, 0.f, 0.f};

    for (int kc = 0; kc < 256; kc += 64) {
        #pragma unroll
        for (int c = 0; c < 4; ++c) { GLDS(gAp[c], lAp[c]); gAp[c] += 64; }
        #pragma unroll
        for (int c = 0; c < 8; ++c) { GLDS(gBp[c], lBp[c]); gBp[c] += 64; }
        __syncthreads();
        #pragma unroll
        for (int sub = 0; sub < 2; ++sub) {
            bf16x8 av[4], bv[8];
            #pragma unroll
            for (int m = 0; m < 4; ++m) av[m] = *(const bf16x8*)(As + aoff[sub][m]);
            #pragma unroll
            for (int n = 0; n < 8; ++n) bv[n] = *(const bf16x8*)(Bs + boff[sub][n]);
            #pragma unroll
            for (int m = 0; m < 4; ++m)
                #pragma unroll
                for (int n = 0; n < 8; ++n)
                    acc[m][n] = __builtin_amdgcn_mfma_f32_16x16x32_bf16(
                        av[m], bv[n], acc[m][n], 0, 0, 0);
        }
        __syncthreads();
    }

    float bA[8];
    #pragma unroll
    for (int n = 0; n < 8; ++n) bA[n] = b1[m0 + wc * 128 + n * 16 + cl];

    // Epilogue: per-wave 8 KB repack buffer (Bs quarters), 2 column halves.
    ushort* Rw = Bs + (w << 12);
    const int rr = l >> 3, rc8 = (l & 7) << 3;
    #pragma unroll
    for (int h = 0; h < 2; ++h) {
        #pragma unroll
        for (int m = 0; m < 4; ++m)
            #pragma unroll
            for (int j = 0; j < 4; ++j) {
                const int lrow = m * 16 + (kg << 2) + j;
                #pragma unroll
                for (int n = 0; n < 4; ++n) {
                    const float v = gelu_f(acc[m][h * 4 + n][j] + bA[h * 4 + n]);
                    const int lcol = (n << 4) + cl;
                    Rw[lrow * 64 + (lcol ^ (((lrow >> 1) & 7) << 3))] = f2b(v);
                }
            }
        #pragma unroll
        for (int p = 0; p < 8; ++p) {
            const int lrow = (p << 3) + rr;
            const bf16x8 v8 = *(const bf16x8*)(
                Rw + lrow * 64 + (rc8 ^ (((lrow >> 1) & 7) << 3)));
            const size_t grow = (size_t)(n0 + wr * 64 + lrow);
            const int gcol = m0 + wc * 128 + h * 64 + rc8;
            *(bf16x8*)(Cb + grow * 1024 + gcol) = v8;
        }
    }
}

// ---------------------------------------------------------------------------
// Full-row GEMM + fused residual/LN, col-split, BK=64, bf16 residual stream.
// v = X@W^T + b1 (+b2) (+E[idx]) (+Fres[idx] if ACC_F).
// WRV: Fres = v (bf16). LNOUT: 0 none; 1 Yb=LN(v); 2 Fres=LN(v); 3 both;
// 4 Fres += LN(v).  K must be a multiple of 64.
// ---------------------------------------------------------------------------
template<bool ADD_E, bool ACC_F, bool WRV, int LNOUT, bool HASB2>
__global__ __launch_bounds__(256)
void growln_k(const ushort* __restrict__ X, const ushort* __restrict__ W,
              const float* __restrict__ b1, const float* __restrict__ b2,
              const ushort* __restrict__ E, const float* __restrict__ g,
              const float* __restrict__ bt, ushort* __restrict__ Fres,
              ushort* __restrict__ Yb, int K)
{
    __shared__ ushort As[32 * 64];     // 4 KB
    __shared__ ushort Bs[256 * 64];    // 32 KB
    __shared__ float sred[32][2];
    __shared__ float qred[32][2];
    const int tid = threadIdx.x;
    const int w = tid >> 6, l = tid & 63;
    const int n0 = blockIdx.x << 5;
    const int rowg = w >> 1, colg = w & 1;

    const int ric = l >> 3, sl = l & 7;
    const ushort* gB[8]; ushort* lB[8];
    #pragma unroll
    for (int c = 0; c < 8; ++c) {
        const int rB = ((w << 3) + c) * 8 + ric;
        gB[c] = W + (size_t)rB * K + ((sl ^ (rB & 7)) << 3);
        lB[c] = Bs + (((w << 3) + c) << 9);
    }
    const int rA = (w << 3) + ric;
    const ushort* gA = X + (size_t)(n0 + rA) * K + ((sl ^ (rA & 7)) << 3);
    ushort* lA = As + (w << 9);

    const int cl = l & 15, kg = l >> 4;
    const int ar = rowg * 16 + cl;
    int aoff[2], boff[2][8];
    #pragma unroll
    for (int sub = 0; sub < 2; ++sub) {
        const int s = sub * 4 + kg;
        aoff[sub] = ar * 64 + ((s ^ (ar & 7)) << 3);
        #pragma unroll
        for (int n = 0; n < 8; ++n) {
            const int br = colg * 128 + n * 16 + cl;
            boff[sub][n] = br * 64 + ((s ^ (br & 7)) << 3);
        }
    }

    f32x4 acc[8];
    #pragma unroll
    for (int n = 0; n < 8; ++n) acc[n] = (f32x4){0.f, 0.f, 0.f, 0.f};

    for (int kc = 0; kc < K; kc += 64) {
        #pragma unroll
        for (int c = 0; c < 8; ++c) { GLDS(gB[c], lB[c]); gB[c] += 64; }
        GLDS(gA, lA); gA += 64;
        __syncthreads();
        #pragma unroll
        for (int sub = 0; sub < 2; ++sub) {
            const bf16x8 av = *(const bf16x8*)(As + aoff[sub]);
            #pragma unroll
            for (int n = 0; n < 8; ++n) {
                const bf16x8 bv = *(const bf16x8*)(Bs + boff[sub][n]);
                acc[n] = __builtin_amdgcn_mfma_f32_16x16x32_bf16(av, bv, acc[n], 0, 0, 0);
            }
        }
        __syncthreads();
    }

    float bA[8];
    #pragma unroll
    for (int n = 0; n < 8; ++n) {
        const int col = colg * 128 + n * 16 + cl;
        float v = (b1 != nullptr) ? b1[col] : 0.0f;
        if (HASB2) v += b2[col];
        bA[n] = v;
    }
    float gg[8], bb[8];
    if (LNOUT > 0) {
        #pragma unroll
        for (int n = 0; n < 8; ++n) {
            const int col = colg * 128 + n * 16 + cl;
            gg[n] = g[col]; bb[n] = bt[col];
        }
    }

    #pragma unroll
    for (int j = 0; j < 4; ++j) {
        const int lrow = rowg * 16 + (kg << 2) + j;
        const size_t rb = (size_t)(n0 + lrow) << 8;
        float s = 0.0f;
        #pragma unroll
        for (int n = 0; n < 8; ++n) {
            const size_t idx = rb + colg * 128 + n * 16 + cl;
            float x = acc[n][j] + bA[n];
            if (ADD_E) x += b2f(E[idx]);
            if (ACC_F) x += b2f(Fres[idx]);
            acc[n][j] = x; s += x;
        }
        if (WRV) {
            #pragma unroll
            for (int n = 0; n < 8; ++n)
                Fres[rb + colg * 128 + n * 16 + cl] = f2b(acc[n][j]);
        }
        if (LNOUT > 0) {
            #pragma unroll
            for (int o = 1; o < 16; o <<= 1) s += __shfl_xor(s, o);
            if (cl == 0) sred[lrow][colg] = s;
        }
    }
    if (LNOUT > 0) {
        __syncthreads();
        float mu[4];
        #pragma unroll
        for (int j = 0; j < 4; ++j) {
            const int lrow = rowg * 16 + (kg << 2) + j;
            mu[j] = (sred[lrow][0] + sred[lrow][1]) * (1.0f / 256.0f);
            float q = 0.0f;
            #pragma unroll
            for (int n = 0; n < 8; ++n) { const float d = acc[n][j] - mu[j]; q += d * d; }
            #pragma unroll
            for (int o = 1; o < 16; o <<= 1) q += __shfl_xor(q, o);
            if (cl == 0) qred[lrow][colg] = q;
        }
        __syncthreads();
        #pragma unroll
        for (int j = 0; j < 4; ++j) {
            const int lrow = rowg * 16 + (kg << 2) + j;
            const size_t rb = (size_t)(n0 + lrow) << 8;
            const float rstd = rsqrtf((qred[lrow][0] + qred[lrow][1]) * (1.0f / 256.0f) + 1e-5f);
            #pragma unroll
            for (int n = 0; n < 8; ++n) {
                const float y = (acc[n][j] - mu[j]) * rstd * gg[n] + bb[n];
                const size_t idx = rb + colg * 128 + n * 16 + cl;
                if (LNOUT & 1) Yb[idx] = f2b(y);
                if (LNOUT == 2 || LNOUT == 3) Fres[idx] = f2b(y);
                if (LNOUT == 4) Fres[idx] = f2b(b2f(Fres[idx]) + y);
            }
        }
    }
}

// ---------------------------------------------------------------------------
// Row LayerNorm (standalone), BF16 input. One wave/row, 4 rows/block.
// ---------------------------------------------------------------------------
__global__ __launch_bounds__(256)
void ln_k(const ushort* __restrict__ X, const float* __restrict__ g,
          const float* __restrict__ bt, ushort* __restrict__ Yb)
{
    const int lane = threadIdx.x & 63;
    const int row  = (blockIdx.x << 2) + (threadIdx.x >> 6);
    const size_t base = (size_t)row * Dm + (lane << 2);
    const ushort4 u = *reinterpret_cast<const ushort4*>(&X[base]);
    const float v0 = b2f(u.x), v1 = b2f(u.y), v2 = b2f(u.z), v3 = b2f(u.w);
    float s = v0 + v1 + v2 + v3;
    #pragma unroll
    for (int o = 1; o < 64; o <<= 1) s += __shfl_xor(s, o);
    const float mu = s * (1.0f / 256.0f);
    const float d0 = v0 - mu, d1 = v1 - mu, d2 = v2 - mu, d3 = v3 - mu;
    float q = d0*d0 + d1*d1 + d2*d2 + d3*d3;
    #pragma unroll
    for (int o = 1; o < 64; o <<= 1) q += __shfl_xor(q, o);
    const float rstd = rsqrtf(q * (1.0f / 256.0f) + 1e-5f);
    const int c = lane << 2;
    const float4 gg = *reinterpret_cast<const float4*>(&g[c]);
    const float4 bb = *reinterpret_cast<const float4*>(&bt[c]);
    ushort4 ub;
    ub.x = f2b(d0*rstd*gg.x + bb.x); ub.y = f2b(d1*rstd*gg.y + bb.y);
    ub.z = f2b(d2*rstd*gg.z + bb.z); ub.w = f2b(d3*rstd*gg.w + bb.w);
    *reinterpret_cast<ushort4*>(&Yb[base]) = ub;
}

// ---------------------------------------------------------------------------
// Cross-attention core, bf16 in/out, fp32 math. One (b,h) per block.
// ---------------------------------------------------------------------------
__global__ __launch_bounds__(256)
void attn_k(const ushort* __restrict__ Q, const ushort* __restrict__ K,
            const ushort* __restrict__ V, ushort* __restrict__ O)
{
    __shared__ float Qs[32][33], Ks[32][33], Vs[32][33], Ss[32][33];
    const int bh = blockIdx.x;
    const int b = bh >> 3, h = bh & 7;
    const int tid = threadIdx.x;
    const int r  = tid >> 3;
    const int c4 = (tid & 7) << 2;
    const size_t base = ((size_t)b * Lseq + r) * Dm + h * 32 + c4;
    {
        const ushort4 q = *reinterpret_cast<const ushort4*>(&Q[base]);
        Qs[r][c4+0]=b2f(q.x); Qs[r][c4+1]=b2f(q.y); Qs[r][c4+2]=b2f(q.z); Qs[r][c4+3]=b2f(q.w);
        const ushort4 k = *reinterpret_cast<const ushort4*>(&K[base]);
        Ks[r][c4+0]=b2f(k.x); Ks[r][c4+1]=b2f(k.y); Ks[r][c4+2]=b2f(k.z); Ks[r][c4+3]=b2f(k.w);
        const ushort4 v = *reinterpret_cast<const ushort4*>(&V[base]);
        Vs[r][c4+0]=b2f(v.x); Vs[r][c4+1]=b2f(v.y); Vs[r][c4+2]=b2f(v.z); Vs[r][c4+3]=b2f(v.w);
    }
    __syncthreads();
    float sc[4] = {0.f, 0.f, 0.f, 0.f};
    #pragma unroll
    for (int d = 0; d < 32; ++d) {
        const float qv = Qs[r][d];
        #pragma unroll
        for (int j = 0; j < 4; ++j) sc[j] = fmaf(qv, Ks[c4+j][d], sc[j]);
    }
    #pragma unroll
    for (int j = 0; j < 4; ++j) sc[j] *= 0.17677669529663687f;
    float mx = fmaxf(fmaxf(sc[0], sc[1]), fmaxf(sc[2], sc[3]));
    #pragma unroll
    for (int o = 1; o < 8; o <<= 1) mx = fmaxf(mx, __shfl_xor(mx, o));
    float sum = 0.f;
    #pragma unroll
    for (int j = 0; j < 4; ++j) { sc[j] = __expf(sc[j] - mx); sum += sc[j]; }
    #pragma unroll
    for (int o = 1; o < 8; o <<= 1) sum += __shfl_xor(sum, o);
    const float inv = 1.0f / sum;
    #pragma unroll
    for (int j = 0; j < 4; ++j) Ss[r][c4+j] = sc[j] * inv;
    __syncthreads();
    float o4[4] = {0.f, 0.f, 0.f, 0.f};
    #pragma unroll
    for (int k = 0; k < 32; ++k) {
        const float wv = Ss[r][k];
        #pragma unroll
        for (int j = 0; j < 4; ++j) o4[j] = fmaf(wv, Vs[k][c4+j], o4[j]);
    }
    ushort4 ob; ob.x=f2b(o4[0]); ob.y=f2b(o4[1]); ob.z=f2b(o4[2]); ob.w=f2b(o4[3]);
    *reinterpret_cast<ushort4*>(&O[base]) = ob;
}

// ---------------------------------------------------------------------------
// XB GEMM: XB[n,s] = sum_d X[n,d] * Bw[s,d]   (N x 16, K=256, bf16 out)
// ---------------------------------------------------------------------------
__global__ __launch_bounds__(256)
void xb_gemm(const ushort* __restrict__ X, const ushort* __restrict__ Bw,
             ushort* __restrict__ XB)
{
    __shared__ ushort As[128 * 32];
    __shared__ ushort Bsf[16 * 256];
    const int tid = threadIdx.x;
    const int w = tid >> 6, l = tid & 63;
    const int n0 = blockIdx.x << 7;
    #pragma unroll
    for (int rep = 0; rep < 2; ++rep) {
        const int u = (rep << 8) + tid;
        const int r = u >> 5;
        const int c8 = (u & 31) << 3;
        const int di = (r * 256 + c8) ^ ((r & 7) << 3);
        *(bf16x8*)(Bsf + di) = *(const bf16x8*)(Bw + r * 256 + c8);
    }
    const int ric = l >> 2, slot = l & 3;
    const int rL0 = (w << 4) + ric, rL1 = rL0 + 64;
    const int sw0 = slot ^ ((rL0 >> 1) & 3), sw1 = slot ^ ((rL1 >> 1) & 3);
    const ushort* gA0 = X + (size_t)(n0 + rL0) * 256 + (sw0 << 3);
    const ushort* gA1 = X + (size_t)(n0 + rL1) * 256 + (sw1 << 3);
    ushort* lA0 = As + (w << 9);
    ushort* lA1 = As + ((w + 4) << 9);
    const int cl = l & 15, kg = l >> 4;
    int aoff[2];
    #pragma unroll
    for (int m = 0; m < 2; ++m) {
        const int r = w * 32 + m * 16 + cl;
        aoff[m] = r * 32 + ((kg ^ ((r >> 1) & 3)) << 3);
    }
    f32x4 acc[2] = {(f32x4){0.f,0.f,0.f,0.f}, (f32x4){0.f,0.f,0.f,0.f}};
    for (int kc = 0; kc < 256; kc += 32) {
        GLDS(gA0, lA0); GLDS(gA1, lA1);
        gA0 += 32; gA1 += 32;
        __syncthreads();
        const bf16x8 av0 = *(const bf16x8*)(As + aoff[0]);
        const bf16x8 av1 = *(const bf16x8*)(As + aoff[1]);
        const int bidx = (cl * 256 + kc + (kg << 3)) ^ ((cl & 7) << 3);
        const bf16x8 bv = *(const bf16x8*)(Bsf + bidx);
        acc[0] = __builtin_amdgcn_mfma_f32_16x16x32_bf16(av0, bv, acc[0], 0, 0, 0);
        acc[1] = __builtin_amdgcn_mfma_f32_16x16x32_bf16(av1, bv, acc[1], 0, 0, 0);
        __syncthreads();
    }
    #pragma unroll
    for (int m = 0; m < 2; ++m)
        #pragma unroll
        for (int j = 0; j < 4; ++j) {
            const int row = n0 + w * 32 + m * 16 + (kg << 2) + j;
            XB[(size_t)row * 16 + cl] = f2b(acc[m][j]);
        }
}

// ---------------------------------------------------------------------------
// powT: T[t*16+s'][tau*16+s] = (A^(t-tau))[s'][s] for t>=tau else 0.
// ---------------------------------------------------------------------------
__global__ __launch_bounds__(256)
void powT_k(const float* __restrict__ A_all, ushort* __restrict__ T_all)
{
    __shared__ float P[2][16][16];
    __shared__ float Asm[16][16];
    const int layer = blockIdx.x;
    const float* A = A_all + layer * 256;
    ushort* T = T_all + (size_t)layer * 262144;
    const int tid = threadIdx.x;
    const int i = tid >> 4, j = tid & 15;
    Asm[i][j] = A[tid];
    const bf16x8 z = {0,0,0,0,0,0,0,0};
    for (int u = tid; u < 32768; u += 256)
        *(bf16x8*)(T + (size_t)u * 8) = z;
    P[0][i][j] = (i == j) ? 1.0f : 0.0f;
    __syncthreads();
    for (int k = 0; k < 32; ++k) {
        const float pv = P[k & 1][i][j];
        const ushort pb = f2b(pv);
        for (int tau = 0; tau + k < 32; ++tau)
            T[(size_t)((tau + k) * 16 + i) * 512 + tau * 16 + j] = pb;
        float acc = 0.0f;
        #pragma unroll
        for (int l2 = 0; l2 < 16; ++l2) acc = fmaf(P[k & 1][i][l2], Asm[l2][j], acc);
        P[(k & 1) ^ 1][i][j] = acc;
        __syncthreads();
    }
}

// zero Hpad (32768 x 64 bf16)
__global__ __launch_bounds__(256)
void zeroH_k(ushort* __restrict__ Hp)
{
    const int i = blockIdx.x * 256 + threadIdx.x;
    const bf16x8 z = {0,0,0,0,0,0,0,0};
    *(bf16x8*)(Hp + (size_t)i * 8) = z;
}

// W_scpad[i][m][s] (stride 64): s<16 = sum_d sw*C, s in [16,64) = 0
__global__ __launch_bounds__(256)
void wsc_k(const float* __restrict__ sw, const float* __restrict__ Cc,
           ushort* __restrict__ Wp)
{
    const int i = blockIdx.x >> 4;
    const int m = ((blockIdx.x & 15) << 4) + (threadIdx.x >> 4);
    const int s = threadIdx.x & 15;
    const float* swr = sw + ((size_t)i << 16) + (m << 8);
    const float* cc  = Cc + ((size_t)i << 12) + s;
    float acc = 0.0f;
    #pragma unroll 8
    for (int d = 0; d < 256; ++d) acc = fmaf(swr[d], cc[d << 4], acc);
    ushort* o = Wp + ((size_t)i << 14) + (m << 6);
    o[s] = f2b(acc);
    o[s + 16] = 0; o[s + 32] = 0; o[s + 48] = 0;
}

// mean over L (bf16 in, bf16 out): G[b,d] = mean_t X[b,t,d]
__global__ __launch_bounds__(256)
void meanL_k(const ushort* __restrict__ X, ushort* __restrict__ G)
{
    const int idx = blockIdx.x * 256 + threadIdx.x;
    const int b = idx >> 8, d = idx & 255;
    const ushort* xp = X + (size_t)b * (Lseq * Dm) + d;
    float s = 0.0f;
    #pragma unroll
    for (int t = 0; t < Lseq; ++t) s += b2f(xp[t << 8]);
    G[idx] = f2b(s * (1.0f / 32.0f));
}

__global__ __launch_bounds__(256)
void fillw_k(float* __restrict__ out)
{
    const int i = blockIdx.x * 256 + threadIdx.x;
    const float wm = 1.0f / 32.0f;
    out[i] = wm / (wm + wm + 1e-6f);
}

__global__ __launch_bounds__(256)
void cast_k(const float* __restrict__ src, ushort* __restrict__ dst, int n4)
{
    const int i = blockIdx.x * 256 + threadIdx.x;
    if (i < n4) {
        const float4 v = reinterpret_cast<const float4*>(src)[i];
        ushort4 o; o.x = f2b(v.x); o.y = f2b(v.y); o.z = f2b(v.z); o.w = f2b(v.w);
        reinterpret_cast<ushort4*>(dst)[i] = o;
    }
}

__global__ __launch_bounds__(256)
void cast_inw_k(const float* __restrict__ src, ushort* __restrict__ dst)
{
    const int i = blockIdx.x * 256 + threadIdx.x;
    const int blk = i >> 14, rem = i & 16383;
    const float4 v = reinterpret_cast<const float4*>(
        src + (size_t)blk * 131072 + 65536)[rem];
    ushort4 o; o.x = f2b(v.x); o.y = f2b(v.y); o.z = f2b(v.z); o.w = f2b(v.w);
    reinterpret_cast<ushort4*>(dst)[i] = o;
}

extern "C" void kernel_launch(void* const* d_in, const int* in_sizes, int n_in,
                              void* d_out, int out_size, void* d_ws, size_t ws_size,
                              hipStream_t stream)
{
    const float* ble_f   = (const float*)d_in[0];
    const float* vis_f   = (const float*)d_in[1];
    const float* bp_w    = (const float*)d_in[2];
    const float* bp_b    = (const float*)d_in[3];
    const float* bp_emb  = (const float*)d_in[4];
    const float* bp_g    = (const float*)d_in[5];
    const float* bp_beta = (const float*)d_in[6];
    const float* vp_w    = (const float*)d_in[7];
    const float* vp_b    = (const float*)d_in[8];
    const float* vp_emb  = (const float*)d_in[9];
    const float* vp_g    = (const float*)d_in[10];
    const float* vp_beta = (const float*)d_in[11];
    const float* a_qw    = (const float*)d_in[12];
    const float* a_qb    = (const float*)d_in[13];
    const float* a_kw    = (const float*)d_in[14];
    const float* a_kb    = (const float*)d_in[15];
    const float* a_vw    = (const float*)d_in[16];
    const float* a_vb    = (const float*)d_in[17];
    const float* a_ow    = (const float*)d_in[18];
    const float* a_ob    = (const float*)d_in[19];
    const float* a_g     = (const float*)d_in[20];
    const float* a_beta  = (const float*)d_in[21];
    const float* m_ln1_g = (const float*)d_in[22];
    const float* m_ln1_b = (const float*)d_in[23];
    const float* m_in_w  = (const float*)d_in[24];
    const float* m_in_b  = (const float*)d_in[25];
    const float* m_A     = (const float*)d_in[26];
    const float* m_B     = (const float*)d_in[27];
    const float* m_C     = (const float*)d_in[28];
    const float* m_gw    = (const float*)d_in[29];
    const float* m_gb    = (const float*)d_in[30];
    const float* m_sw    = (const float*)d_in[31];
    const float* m_sb    = (const float*)d_in[32];
    const float* m_ln2_g = (const float*)d_in[33];
    const float* m_ln2_b = (const float*)d_in[34];
    const float* m_f1w   = (const float*)d_in[35];
    const float* m_f1b   = (const float*)d_in[36];
    const float* m_f2w   = (const float*)d_in[37];
    const float* m_f2b   = (const float*)d_in[38];
    const float* fin_g   = (const float*)d_in[39];
    const float* fin_beta= (const float*)d_in[40];
    const float* fin_w   = (const float*)d_in[41];
    const float* fin_b   = (const float*)d_in[42];

    float* out = (float*)d_out;
    float* ws  = (float*)d_ws;
    const size_t NDf = (size_t)NROW * Dm;

    ushort* F_res = (ushort*)ws;             // bf16 residual stream
    ushort* Gpool = F_res + NDf;
    float*  F2    = ws + 3 * NDf;            // overlay arena only
    ushort* S0 = (ushort*)(ws + 4 * NDf);
    ushort* S1 = S0 + NDf;
    ushort* S2 = S1 + NDf;
    ushort* S3 = S2 + NDf;
    ushort* S4 = S3 + NDf;
    ushort* Wa = S4 + NDf;
    ushort* W_bp  = Wa;
    ushort* W_vp  = W_bp + 32768;
    ushort* W_q   = W_vp + 65536;
    ushort* W_k   = W_q + 131072;
    ushort* W_v   = W_k + 131072;
    ushort* W_o   = W_v + 131072;
    ushort* W_g   = W_o + 131072;
    ushort* W_in  = W_g + 393216;
    ushort* W_f1  = W_in + 393216;
    ushort* W_f2  = W_f1 + 1572864;
    ushort* W_fin = W_f2 + 1572864;
    ushort* W_sc  = W_fin + 65536;          // 6 * 256*64 (stride 64)
    ushort* Hpad  = W_sc + 98304;           // 32768*64 (stride 64)
    ushort* B_ble = (ushort*)F2;
    ushort* B_vis = B_ble + (size_t)NROW * 128;
    ushort* T_all = (ushort*)F2;
    ushort* W_bm  = T_all + 1572864;
    ushort* XBuf  = W_bm + 24576;

    const dim3 blk(256);
    auto cgrid = [](int n4) { return dim3((n4 + 255) / 256); };

    cast_k<<<cgrid(1048576), blk, 0, stream>>>(ble_f, B_ble, 1048576);
    cast_k<<<cgrid(2097152), blk, 0, stream>>>(vis_f, B_vis, 2097152);
    cast_k<<<cgrid(8192),   blk, 0, stream>>>(bp_w, W_bp, 8192);
    cast_k<<<cgrid(16384),  blk, 0, stream>>>(vp_w, W_vp, 16384);
    cast_k<<<cgrid(32768),  blk, 0, stream>>>(a_qw, W_q, 32768);
    cast_k<<<cgrid(32768),  blk, 0, stream>>>(a_kw, W_k, 32768);
    cast_k<<<cgrid(32768),  blk, 0, stream>>>(a_vw, W_v, 32768);
    cast_k<<<cgrid(32768),  blk, 0, stream>>>(a_ow, W_o, 32768);
    cast_k<<<cgrid(98304),  blk, 0, stream>>>(m_gw, W_g, 98304);
    cast_k<<<cgrid(393216), blk, 0, stream>>>(m_f1w, W_f1, 393216);
    cast_k<<<cgrid(393216), blk, 0, stream>>>(m_f2w, W_f2, 393216);
    cast_k<<<cgrid(16384),  blk, 0, stream>>>(fin_w, W_fin, 16384);
    cast_inw_k<<<cgrid(98304), blk, 0, stream>>>(m_in_w, W_in);
    wsc_k<<<96, blk, 0, stream>>>(m_sw, m_C, W_sc);

    auto gg = [](int M, int N) { return dim3(M / 128, N / 128); };
    const dim3 gRow(NROW / 32);

    // ---- input projections + fused LN (bf16 LN out only) ----
    growln_k<false,false,false,1,true><<<gRow, blk, 0, stream>>>(
        B_ble, W_bp, bp_b, bp_emb, nullptr, bp_g, bp_beta, nullptr, S0, 128);
    growln_k<false,false,false,1,true><<<gRow, blk, 0, stream>>>(
        B_vis, W_vp, vp_b, vp_emb, nullptr, vp_g, vp_beta, nullptr, S1, 256);

    // ---- two cross-attentions (residual from bf16 S0/S1) ----
    for (int a = 0; a < 2; ++a) {
        const ushort* qin_b = (a == 0) ? S0 : S1;
        const ushort* kin_b = (a == 0) ? S1 : S0;
        const size_t wo = (size_t)a * 65536;
        const size_t bo = (size_t)a * 256;
        mgemm<0,true,0,0><<<gg(256, NROW), blk, 0, stream>>>(
            qin_b, W_q + wo, nullptr, a_qb + bo, nullptr, nullptr, S4, nullptr, 256, 256);
        mgemm<0,true,0,2><<<gg(256, NROW), blk, 0, stream>>>(
            kin_b, W_k + wo, W_v + wo, a_kb + bo, a_vb + bo, nullptr, S2, S3, 256, 256);
        attn_k<<<Bsz * 8, blk, 0, stream>>>(S4, S2, S3, S4);
        if (a == 0)
            growln_k<true,false,false,2,false><<<gRow, blk, 0, stream>>>(
                S4, W_o + wo, a_ob + bo, nullptr, qin_b, a_g + bo, a_beta + bo, F_res, nullptr, 256);
        else
            growln_k<true,false,false,4,false><<<gRow, blk, 0, stream>>>(
                S4, W_o + wo, a_ob + bo, nullptr, qin_b, a_g + bo, a_beta + bo, F_res, nullptr, 256);
    }

    // ---- scan matrices (overlay F2, now dead) ----
    powT_k<<<6, blk, 0, stream>>>(m_A, T_all);
    cast_k<<<cgrid(6144), blk, 0, stream>>>(m_B, W_bm, 6144);
    zeroH_k<<<1024, blk, 0, stream>>>(Hpad);

    // ln1 of block 0
    ln_k<<<NROW/4, blk, 0, stream>>>(F_res, m_ln1_g, m_ln1_b, S0);

    // ---- 6 mamba blocks ----
    for (int i = 0; i < 6; ++i) {
        mgemm<0,true,0,1><<<gg(256, NROW), blk, 0, stream>>>(
            S0, W_g + (size_t)i*65536, W_in + (size_t)i*65536,
            m_gb + i*256, m_in_b + (size_t)i*512 + 256, nullptr, S2, nullptr, 256, 256);
        xb_gemm<<<NROW/128, blk, 0, stream>>>(S2, W_bm + (size_t)i*4096, XBuf);
        mgemm<0,true,1,0><<<gg(512, 1024), blk, 0, stream>>>(
            XBuf, T_all + (size_t)i*262144, nullptr, nullptr, nullptr, nullptr, Hpad, nullptr, 512, 512);
        // F_res += H@(sw@C)^T + sb (bf16 residual); S0 = ln2(F_res). K=64 (padded)
        growln_k<false,true,true,1,false><<<gRow, blk, 0, stream>>>(
            Hpad, W_sc + (size_t)i*16384, m_sb + i*256, nullptr, nullptr,
            m_ln2_g + i*256, m_ln2_b + i*256, F_res, S0, 64);
        // S1 = gelu(S0 @ W1^T + b1)  — wide 128x256 tile kernel
        f1_gemm<<<dim3(4, 256), blk, 0, stream>>>(
            S0, W_f1 + (size_t)i*262144, m_f1b + i*1024, S1);
        if (i < 5)
            growln_k<false,true,true,1,false><<<gRow, blk, 0, stream>>>(
                S1, W_f2 + (size_t)i*262144, m_f2b + i*256, nullptr, nullptr,
                m_ln1_g + (i+1)*256, m_ln1_b + (i+1)*256, F_res, S0, 1024);
        else
            growln_k<false,true,true,0,false><<<gRow, blk, 0, stream>>>(
                S1, W_f2 + (size_t)i*262144, m_f2b + i*256, nullptr, nullptr,
                nullptr, nullptr, F_res, nullptr, 1024);
    }

    // ---- head ----
    meanL_k<<<(Bsz * Dm) / 256, blk, 0, stream>>>(F_res, Gpool);
    ln_k<<<Bsz/4, blk, 0, stream>>>(Gpool, fin_g, fin_beta, S1);
    mgemm<2,false,0,0><<<gg(256, Bsz), blk, 0, stream>>>(
        S1, W_fin, nullptr, fin_b, nullptr, out, nullptr, nullptr, 256, 256);
    fillw_k<<<8, blk, 0, stream>>>(out + (size_t)Bsz * Dm);
}

// Round 14
// 1097.064 us; speedup vs baseline: 1.0364x; 1.0364x over previous
//
#include <hip/hip_runtime.h>
#include <hip/hip_bf16.h>
#include <math.h>

static constexpr int Bsz  = 1024;
static constexpr int Lseq = 32;
static constexpr int Dm   = 256;
static constexpr int NROW = Bsz * Lseq;   // 32768

typedef __attribute__((ext_vector_type(8))) short bf16x8;
typedef __attribute__((ext_vector_type(4))) float f32x4;

__device__ __forceinline__ float sigm_f(float x) {
    return 1.0f / (1.0f + __expf(-x));
}
__device__ __forceinline__ float gelu_f(float x) {
    const float u = x * (0.7978845608028654f + 0.0356774081f * x * x);
    return x * sigm_f(2.0f * u);
}
__device__ __forceinline__ float b2f(ushort u) {
    union { float f; uint v; } t; t.v = ((uint)u) << 16; return t.f;
}
__device__ __forceinline__ ushort f2b(float f) {
    union { float f; uint v; } t; t.f = f;
    const uint lsb = (t.v >> 16) & 1u;
    t.v += 0x7fffu + lsb;
    return (ushort)(t.v >> 16);
}

#define GLDS(gp, lp) __builtin_amdgcn_global_load_lds( \
    (const __attribute__((address_space(1))) void*)(gp), \
    (__attribute__((address_space(3))) void*)(lp), 16, 0, 0)

// BK=64 staging scheme: chunk = 8 rows x 64 cols bf16 (1 KB);
// lane l -> row l>>3, 16B-slot l&7; stored slot = s ^ (row & 7).
// LDS ushort idx (row r, k-slot s): r*64 + ((s ^ (r&7)) << 3).

// ---------------------------------------------------------------------------
// bf16 MFMA GEMM, 128x128 tile, BK=64, 256 threads (round-12 proven version).
// ACT: 0 none, 1 sigm, 2 gelu. OMAP: 1 = scan-H remap (stride-64 Hpad) with
// triangular K-limit (T block-lower-triangular: k >= m0+128 contributes 0).
// DUAL: 1 gateIn: Cb = sigm(A@W+b1)*(A@W2+b2); 2: Cb=A@W+b1, Cb2=A@W2+b2.
// XCD-aware bijective block swizzle + LDS-repacked coalesced bf16 epilogue.
// ---------------------------------------------------------------------------
template<int ACT, bool OUTBF, int OMAP, int DUAL>
__global__ __launch_bounds__(256)
void mgemm(const ushort* __restrict__ X, const ushort* __restrict__ W,
           const ushort* __restrict__ W2,
           const float* __restrict__ b1, const float* __restrict__ b2,
           float* __restrict__ Cf, ushort* __restrict__ Cb,
           ushort* __restrict__ Cb2, int K, int M)
{
    __shared__ ushort As[8192];                 // 128 x 64
    __shared__ ushort Bs[8192];
    __shared__ ushort Bs2[DUAL ? 8192 : 8];
    const int tid = threadIdx.x;
    const int w = tid >> 6, l = tid & 63;

    int f = blockIdx.y * gridDim.x + blockIdx.x;
    const int nwg = gridDim.x * gridDim.y;
    if ((nwg & 7) == 0) f = (f & 7) * (nwg >> 3) + (f >> 3);
    const int n0 = (f / gridDim.x) << 7;
    const int m0 = (f % gridDim.x) << 7;

    const int ric = l >> 3;          // row in chunk 0..7
    const int sl  = l & 7;           // 16B slot 0..7
    const ushort* gAp[4]; const ushort* gBp[4]; const ushort* gCp[DUAL ? 4 : 1];
    ushort* lAp[4]; ushort* lBp[4]; ushort* lCp[DUAL ? 4 : 1];
    #pragma unroll
    for (int c = 0; c < 4; ++c) {
        const int r = ((w << 2) + c) * 8 + ric;
        const int eo = (sl ^ (r & 7)) << 3;
        gAp[c] = X + (size_t)(n0 + r) * K + eo;
        gBp[c] = W + (size_t)(m0 + r) * K + eo;
        lAp[c] = As + (((w << 2) + c) << 9);
        lBp[c] = Bs + (((w << 2) + c) << 9);
        if constexpr (DUAL) {
            gCp[c] = W2 + (size_t)(m0 + r) * K + eo;
            lCp[c] = Bs2 + (((w << 2) + c) << 9);
        }
    }

    const int wr = (w >> 1) & 1, wc = w & 1;
    const int cl = l & 15, kg = l >> 4;
    int aoff[2][4], boff[2][4];
    #pragma unroll
    for (int sub = 0; sub < 2; ++sub) {
        const int s = sub * 4 + kg;
        #pragma unroll
        for (int m = 0; m < 4; ++m) {
            const int r = wr * 64 + m * 16 + cl;
            aoff[sub][m] = r * 64 + ((s ^ (r & 7)) << 3);
        }
        #pragma unroll
        for (int n = 0; n < 4; ++n) {
            const int r = wc * 64 + n * 16 + cl;
            boff[sub][n] = r * 64 + ((s ^ (r & 7)) << 3);
        }
    }

    f32x4 acc[4][4];
    f32x4 acc2[DUAL ? 4 : 1][DUAL ? 4 : 1];
    #pragma unroll
    for (int m = 0; m < 4; ++m)
        #pragma unroll
        for (int n = 0; n < 4; ++n) {
            acc[m][n] = (f32x4){0.f, 0.f, 0.f, 0.f};
            if constexpr (DUAL) acc2[m][n] = (f32x4){0.f, 0.f, 0.f, 0.f};
        }

    // Triangular skip for the scan-H GEMM: tile needs only k < m0+128.
    const int Klim = (OMAP == 1) ? (m0 + 128 < K ? m0 + 128 : K) : K;
    for (int kc = 0; kc < Klim; kc += 64) {
        #pragma unroll
        for (int c = 0; c < 4; ++c) {
            GLDS(gAp[c], lAp[c]); gAp[c] += 64;
            GLDS(gBp[c], lBp[c]); gBp[c] += 64;
            if constexpr (DUAL) { GLDS(gCp[c], lCp[c]); gCp[c] += 64; }
        }
        __syncthreads();
        #pragma unroll
        for (int sub = 0; sub < 2; ++sub) {
            bf16x8 av[4], bv[4];
            #pragma unroll
            for (int m = 0; m < 4; ++m) av[m] = *(const bf16x8*)(As + aoff[sub][m]);
            #pragma unroll
            for (int n = 0; n < 4; ++n) bv[n] = *(const bf16x8*)(Bs + boff[sub][n]);
            #pragma unroll
            for (int m = 0; m < 4; ++m)
                #pragma unroll
                for (int n = 0; n < 4; ++n)
                    acc[m][n] = __builtin_amdgcn_mfma_f32_16x16x32_bf16(
                        av[m], bv[n], acc[m][n], 0, 0, 0);
            if constexpr (DUAL) {
                bf16x8 cv[4];
                #pragma unroll
                for (int n = 0; n < 4; ++n) cv[n] = *(const bf16x8*)(Bs2 + boff[sub][n]);
                #pragma unroll
                for (int m = 0; m < 4; ++m)
                    #pragma unroll
                    for (int n = 0; n < 4; ++n)
                        acc2[m][n] = __builtin_amdgcn_mfma_f32_16x16x32_bf16(
                            av[m], cv[n], acc2[m][n], 0, 0, 0);
            }
        }
        __syncthreads();
    }

    const int colb = m0 + wc * 64 + cl;
    const int rowb = n0 + wr * 64 + (kg << 2);
    float biasA[4], biasB[4];
    #pragma unroll
    for (int n = 0; n < 4; ++n) {
        biasA[n] = (b1 != nullptr) ? b1[colb + n * 16] : 0.0f;
        if constexpr (DUAL) biasB[n] = b2[colb + n * 16];
    }

    if constexpr (OUTBF || DUAL != 0) {
        ushort* Rw = (w == 0) ? As : (w == 1) ? As + 4096
                   : (w == 2) ? Bs : Bs + 4096;
        const int rr = l >> 3, rc8 = (l & 7) << 3;
        const int nout = (DUAL == 2) ? 2 : 1;
        for (int which = 0; which < nout; ++which) {
            #pragma unroll
            for (int m = 0; m < 4; ++m)
                #pragma unroll
                for (int j = 0; j < 4; ++j) {
                    const int lrow = m * 16 + (kg << 2) + j;
                    #pragma unroll
                    for (int n = 0; n < 4; ++n) {
                        float v;
                        if (which == 0) {
                            v = acc[m][n][j] + biasA[n];
                            if constexpr (DUAL == 1)
                                v = sigm_f(v) * (acc2[m][n][j] + biasB[n]);
                            else if (ACT == 1) v = sigm_f(v);
                            else if (ACT == 2) v = gelu_f(v);
                        } else {
                            v = acc2[m][n][j] + biasB[n];
                        }
                        const int lcol = (n << 4) + cl;
                        Rw[lrow * 64 + (lcol ^ (((lrow >> 1) & 7) << 3))] = f2b(v);
                    }
                }
            ushort* dst = (which == 0) ? Cb : Cb2;
            #pragma unroll
            for (int p = 0; p < 8; ++p) {
                const int lrow = (p << 3) + rr;
                const bf16x8 v8 = *(const bf16x8*)(
                    Rw + lrow * 64 + (rc8 ^ (((lrow >> 1) & 7) << 3)));
                const size_t grow = (size_t)(n0 + wr * 64 + lrow);
                const int gcol = m0 + wc * 64 + rc8;
                size_t idx;
                if (OMAP == 1) idx = grow * 2048 + ((size_t)(gcol >> 4) << 6) + (gcol & 15);
                else           idx = grow * (size_t)M + gcol;
                *(bf16x8*)(dst + idx) = v8;
            }
        }
    } else {
        #pragma unroll
        for (int m = 0; m < 4; ++m)
            #pragma unroll
            for (int j = 0; j < 4; ++j) {
                const size_t row = (size_t)(rowb + m * 16 + j);
                #pragma unroll
                for (int n = 0; n < 4; ++n) {
                    float v = acc[m][n][j] + biasA[n];
                    if (ACT == 1) v = sigm_f(v);
                    else if (ACT == 2) v = gelu_f(v);
                    Cf[row * (size_t)M + colb + n * 16] = v;
                }
            }
    }
}

// ---------------------------------------------------------------------------
// Full-row GEMM + fused residual/LN, col-split, BK=64, bf16 residual stream.
// v = X@W^T + b1 (+b2) (+E[idx]) (+Fres[idx] if ACC_F).
// WRV: Fres = v (bf16). LNOUT: 0 none; 1 Yb=LN(v); 2 Fres=LN(v); 3 both;
// 4 Fres += LN(v).  K must be a multiple of 64.
// ---------------------------------------------------------------------------
template<bool ADD_E, bool ACC_F, bool WRV, int LNOUT, bool HASB2>
__global__ __launch_bounds__(256)
void growln_k(const ushort* __restrict__ X, const ushort* __restrict__ W,
              const float* __restrict__ b1, const float* __restrict__ b2,
              const ushort* __restrict__ E, const float* __restrict__ g,
              const float* __restrict__ bt, ushort* __restrict__ Fres,
              ushort* __restrict__ Yb, int K)
{
    __shared__ ushort As[32 * 64];     // 4 KB
    __shared__ ushort Bs[256 * 64];    // 32 KB
    __shared__ float sred[32][2];
    __shared__ float qred[32][2];
    const int tid = threadIdx.x;
    const int w = tid >> 6, l = tid & 63;
    const int n0 = blockIdx.x << 5;
    const int rowg = w >> 1, colg = w & 1;

    const int ric = l >> 3, sl = l & 7;
    const ushort* gB[8]; ushort* lB[8];
    #pragma unroll
    for (int c = 0; c < 8; ++c) {
        const int rB = ((w << 3) + c) * 8 + ric;
        gB[c] = W + (size_t)rB * K + ((sl ^ (rB & 7)) << 3);
        lB[c] = Bs + (((w << 3) + c) << 9);
    }
    const int rA = (w << 3) + ric;
    const ushort* gA = X + (size_t)(n0 + rA) * K + ((sl ^ (rA & 7)) << 3);
    ushort* lA = As + (w << 9);

    const int cl = l & 15, kg = l >> 4;
    const int ar = rowg * 16 + cl;
    int aoff[2], boff[2][8];
    #pragma unroll
    for (int sub = 0; sub < 2; ++sub) {
        const int s = sub * 4 + kg;
        aoff[sub] = ar * 64 + ((s ^ (ar & 7)) << 3);
        #pragma unroll
        for (int n = 0; n < 8; ++n) {
            const int br = colg * 128 + n * 16 + cl;
            boff[sub][n] = br * 64 + ((s ^ (br & 7)) << 3);
        }
    }

    f32x4 acc[8];
    #pragma unroll
    for (int n = 0; n < 8; ++n) acc[n] = (f32x4){0.f, 0.f, 0.f, 0.f};

    for (int kc = 0; kc < K; kc += 64) {
        #pragma unroll
        for (int c = 0; c < 8; ++c) { GLDS(gB[c], lB[c]); gB[c] += 64; }
        GLDS(gA, lA); gA += 64;
        __syncthreads();
        #pragma unroll
        for (int sub = 0; sub < 2; ++sub) {
            const bf16x8 av = *(const bf16x8*)(As + aoff[sub]);
            #pragma unroll
            for (int n = 0; n < 8; ++n) {
                const bf16x8 bv = *(const bf16x8*)(Bs + boff[sub][n]);
                acc[n] = __builtin_amdgcn_mfma_f32_16x16x32_bf16(av, bv, acc[n], 0, 0, 0);
            }
        }
        __syncthreads();
    }

    float bA[8];
    #pragma unroll
    for (int n = 0; n < 8; ++n) {
        const int col = colg * 128 + n * 16 + cl;
        float v = (b1 != nullptr) ? b1[col] : 0.0f;
        if (HASB2) v += b2[col];
        bA[n] = v;
    }
    float gg[8], bb[8];
    if (LNOUT > 0) {
        #pragma unroll
        for (int n = 0; n < 8; ++n) {
            const int col = colg * 128 + n * 16 + cl;
            gg[n] = g[col]; bb[n] = bt[col];
        }
    }

    #pragma unroll
    for (int j = 0; j < 4; ++j) {
        const int lrow = rowg * 16 + (kg << 2) + j;
        const size_t rb = (size_t)(n0 + lrow) << 8;
        float s = 0.0f;
        #pragma unroll
        for (int n = 0; n < 8; ++n) {
            const size_t idx = rb + colg * 128 + n * 16 + cl;
            float x = acc[n][j] + bA[n];
            if (ADD_E) x += b2f(E[idx]);
            if (ACC_F) x += b2f(Fres[idx]);
            acc[n][j] = x; s += x;
        }
        if (WRV) {
            #pragma unroll
            for (int n = 0; n < 8; ++n)
                Fres[rb + colg * 128 + n * 16 + cl] = f2b(acc[n][j]);
        }
        if (LNOUT > 0) {
            #pragma unroll
            for (int o = 1; o < 16; o <<= 1) s += __shfl_xor(s, o);
            if (cl == 0) sred[lrow][colg] = s;
        }
    }
    if (LNOUT > 0) {
        __syncthreads();
        float mu[4];
        #pragma unroll
        for (int j = 0; j < 4; ++j) {
            const int lrow = rowg * 16 + (kg << 2) + j;
            mu[j] = (sred[lrow][0] + sred[lrow][1]) * (1.0f / 256.0f);
            float q = 0.0f;
            #pragma unroll
            for (int n = 0; n < 8; ++n) { const float d = acc[n][j] - mu[j]; q += d * d; }
            #pragma unroll
            for (int o = 1; o < 16; o <<= 1) q += __shfl_xor(q, o);
            if (cl == 0) qred[lrow][colg] = q;
        }
        __syncthreads();
        #pragma unroll
        for (int j = 0; j < 4; ++j) {
            const int lrow = rowg * 16 + (kg << 2) + j;
            const size_t rb = (size_t)(n0 + lrow) << 8;
            const float rstd = rsqrtf((qred[lrow][0] + qred[lrow][1]) * (1.0f / 256.0f) + 1e-5f);
            #pragma unroll
            for (int n = 0; n < 8; ++n) {
                const float y = (acc[n][j] - mu[j]) * rstd * gg[n] + bb[n];
                const size_t idx = rb + colg * 128 + n * 16 + cl;
                if (LNOUT & 1) Yb[idx] = f2b(y);
                if (LNOUT == 2 || LNOUT == 3) Fres[idx] = f2b(y);
                if (LNOUT == 4) Fres[idx] = f2b(b2f(Fres[idx]) + y);
            }
        }
    }
}

// ---------------------------------------------------------------------------
// Row LayerNorm (standalone), BF16 input. One wave/row, 4 rows/block.
// ---------------------------------------------------------------------------
__global__ __launch_bounds__(256)
void ln_k(const ushort* __restrict__ X, const float* __restrict__ g,
          const float* __restrict__ bt, ushort* __restrict__ Yb)
{
    const int lane = threadIdx.x & 63;
    const int row  = (blockIdx.x << 2) + (threadIdx.x >> 6);
    const size_t base = (size_t)row * Dm + (lane << 2);
    const ushort4 u = *reinterpret_cast<const ushort4*>(&X[base]);
    const float v0 = b2f(u.x), v1 = b2f(u.y), v2 = b2f(u.z), v3 = b2f(u.w);
    float s = v0 + v1 + v2 + v3;
    #pragma unroll
    for (int o = 1; o < 64; o <<= 1) s += __shfl_xor(s, o);
    const float mu = s * (1.0f / 256.0f);
    const float d0 = v0 - mu, d1 = v1 - mu, d2 = v2 - mu, d3 = v3 - mu;
    float q = d0*d0 + d1*d1 + d2*d2 + d3*d3;
    #pragma unroll
    for (int o = 1; o < 64; o <<= 1) q += __shfl_xor(q, o);
    const float rstd = rsqrtf(q * (1.0f / 256.0f) + 1e-5f);
    const int c = lane << 2;
    const float4 gg = *reinterpret_cast<const float4*>(&g[c]);
    const float4 bb = *reinterpret_cast<const float4*>(&bt[c]);
    ushort4 ub;
    ub.x = f2b(d0*rstd*gg.x + bb.x); ub.y = f2b(d1*rstd*gg.y + bb.y);
    ub.z = f2b(d2*rstd*gg.z + bb.z); ub.w = f2b(d3*rstd*gg.w + bb.w);
    *reinterpret_cast<ushort4*>(&Yb[base]) = ub;
}

// ---------------------------------------------------------------------------
// Cross-attention core, bf16 in/out, fp32 math. One (b,h) per block.
// ---------------------------------------------------------------------------
__global__ __launch_bounds__(256)
void attn_k(const ushort* __restrict__ Q, const ushort* __restrict__ K,
            const ushort* __restrict__ V, ushort* __restrict__ O)
{
    __shared__ float Qs[32][33], Ks[32][33], Vs[32][33], Ss[32][33];
    const int bh = blockIdx.x;
    const int b = bh >> 3, h = bh & 7;
    const int tid = threadIdx.x;
    const int r  = tid >> 3;
    const int c4 = (tid & 7) << 2;
    const size_t base = ((size_t)b * Lseq + r) * Dm + h * 32 + c4;
    {
        const ushort4 q = *reinterpret_cast<const ushort4*>(&Q[base]);
        Qs[r][c4+0]=b2f(q.x); Qs[r][c4+1]=b2f(q.y); Qs[r][c4+2]=b2f(q.z); Qs[r][c4+3]=b2f(q.w);
        const ushort4 k = *reinterpret_cast<const ushort4*>(&K[base]);
        Ks[r][c4+0]=b2f(k.x); Ks[r][c4+1]=b2f(k.y); Ks[r][c4+2]=b2f(k.z); Ks[r][c4+3]=b2f(k.w);
        const ushort4 v = *reinterpret_cast<const ushort4*>(&V[base]);
        Vs[r][c4+0]=b2f(v.x); Vs[r][c4+1]=b2f(v.y); Vs[r][c4+2]=b2f(v.z); Vs[r][c4+3]=b2f(v.w);
    }
    __syncthreads();
    float sc[4] = {0.f, 0.f, 0.f, 0.f};
    #pragma unroll
    for (int d = 0; d < 32; ++d) {
        const float qv = Qs[r][d];
        #pragma unroll
        for (int j = 0; j < 4; ++j) sc[j] = fmaf(qv, Ks[c4+j][d], sc[j]);
    }
    #pragma unroll
    for (int j = 0; j < 4; ++j) sc[j] *= 0.17677669529663687f;
    float mx = fmaxf(fmaxf(sc[0], sc[1]), fmaxf(sc[2], sc[3]));
    #pragma unroll
    for (int o = 1; o < 8; o <<= 1) mx = fmaxf(mx, __shfl_xor(mx, o));
    float sum = 0.f;
    #pragma unroll
    for (int j = 0; j < 4; ++j) { sc[j] = __expf(sc[j] - mx); sum += sc[j]; }
    #pragma unroll
    for (int o = 1; o < 8; o <<= 1) sum += __shfl_xor(sum, o);
    const float inv = 1.0f / sum;
    #pragma unroll
    for (int j = 0; j < 4; ++j) Ss[r][c4+j] = sc[j] * inv;
    __syncthreads();
    float o4[4] = {0.f, 0.f, 0.f, 0.f};
    #pragma unroll
    for (int k = 0; k < 32; ++k) {
        const float wv = Ss[r][k];
        #pragma unroll
        for (int j = 0; j < 4; ++j) o4[j] = fmaf(wv, Vs[k][c4+j], o4[j]);
    }
    ushort4 ob; ob.x=f2b(o4[0]); ob.y=f2b(o4[1]); ob.z=f2b(o4[2]); ob.w=f2b(o4[3]);
    *reinterpret_cast<ushort4*>(&O[base]) = ob;
}

// ---------------------------------------------------------------------------
// XB GEMM: XB[n,s] = sum_d X[n,d] * Bw[s,d]   (N x 16, K=256, bf16 out)
// ---------------------------------------------------------------------------
__global__ __launch_bounds__(256)
void xb_gemm(const ushort* __restrict__ X, const ushort* __restrict__ Bw,
             ushort* __restrict__ XB)
{
    __shared__ ushort As[128 * 32];
    __shared__ ushort Bsf[16 * 256];
    const int tid = threadIdx.x;
    const int w = tid >> 6, l = tid & 63;
    const int n0 = blockIdx.x << 7;
    #pragma unroll
    for (int rep = 0; rep < 2; ++rep) {
        const int u = (rep << 8) + tid;
        const int r = u >> 5;
        const int c8 = (u & 31) << 3;
        const int di = (r * 256 + c8) ^ ((r & 7) << 3);
        *(bf16x8*)(Bsf + di) = *(const bf16x8*)(Bw + r * 256 + c8);
    }
    const int ric = l >> 2, slot = l & 3;
    const int rL0 = (w << 4) + ric, rL1 = rL0 + 64;
    const int sw0 = slot ^ ((rL0 >> 1) & 3), sw1 = slot ^ ((rL1 >> 1) & 3);
    const ushort* gA0 = X + (size_t)(n0 + rL0) * 256 + (sw0 << 3);
    const ushort* gA1 = X + (size_t)(n0 + rL1) * 256 + (sw1 << 3);
    ushort* lA0 = As + (w << 9);
    ushort* lA1 = As + ((w + 4) << 9);
    const int cl = l & 15, kg = l >> 4;
    int aoff[2];
    #pragma unroll
    for (int m = 0; m < 2; ++m) {
        const int r = w * 32 + m * 16 + cl;
        aoff[m] = r * 32 + ((kg ^ ((r >> 1) & 3)) << 3);
    }
    f32x4 acc[2] = {(f32x4){0.f,0.f,0.f,0.f}, (f32x4){0.f,0.f,0.f,0.f}};
    for (int kc = 0; kc < 256; kc += 32) {
        GLDS(gA0, lA0); GLDS(gA1, lA1);
        gA0 += 32; gA1 += 32;
        __syncthreads();
        const bf16x8 av0 = *(const bf16x8*)(As + aoff[0]);
        const bf16x8 av1 = *(const bf16x8*)(As + aoff[1]);
        const int bidx = (cl * 256 + kc + (kg << 3)) ^ ((cl & 7) << 3);
        const bf16x8 bv = *(const bf16x8*)(Bsf + bidx);
        acc[0] = __builtin_amdgcn_mfma_f32_16x16x32_bf16(av0, bv, acc[0], 0, 0, 0);
        acc[1] = __builtin_amdgcn_mfma_f32_16x16x32_bf16(av1, bv, acc[1], 0, 0, 0);
        __syncthreads();
    }
    #pragma unroll
    for (int m = 0; m < 2; ++m)
        #pragma unroll
        for (int j = 0; j < 4; ++j) {
            const int row = n0 + w * 32 + m * 16 + (kg << 2) + j;
            XB[(size_t)row * 16 + cl] = f2b(acc[m][j]);
        }
}

// ---------------------------------------------------------------------------
// powT: T[t*16+s'][tau*16+s] = (A^(t-tau))[s'][s] for t>=tau else 0.
// ---------------------------------------------------------------------------
__global__ __launch_bounds__(256)
void powT_k(const float* __restrict__ A_all, ushort* __restrict__ T_all)
{
    __shared__ float P[2][16][16];
    __shared__ float Asm[16][16];
    const int layer = blockIdx.x;
    const float* A = A_all + layer * 256;
    ushort* T = T_all + (size_t)layer * 262144;
    const int tid = threadIdx.x;
    const int i = tid >> 4, j = tid & 15;
    Asm[i][j] = A[tid];
    const bf16x8 z = {0,0,0,0,0,0,0,0};
    for (int u = tid; u < 32768; u += 256)
        *(bf16x8*)(T + (size_t)u * 8) = z;
    P[0][i][j] = (i == j) ? 1.0f : 0.0f;
    __syncthreads();
    for (int k = 0; k < 32; ++k) {
        const float pv = P[k & 1][i][j];
        const ushort pb = f2b(pv);
        for (int tau = 0; tau + k < 32; ++tau)
            T[(size_t)((tau + k) * 16 + i) * 512 + tau * 16 + j] = pb;
        float acc = 0.0f;
        #pragma unroll
        for (int l2 = 0; l2 < 16; ++l2) acc = fmaf(P[k & 1][i][l2], Asm[l2][j], acc);
        P[(k & 1) ^ 1][i][j] = acc;
        __syncthreads();
    }
}

// zero Hpad (32768 x 64 bf16)
__global__ __launch_bounds__(256)
void zeroH_k(ushort* __restrict__ Hp)
{
    const int i = blockIdx.x * 256 + threadIdx.x;
    const bf16x8 z = {0,0,0,0,0,0,0,0};
    *(bf16x8*)(Hp + (size_t)i * 8) = z;
}

// W_scpad[i][m][s] (stride 64): s<16 = sum_d sw*C, s in [16,64) = 0
__global__ __launch_bounds__(256)
void wsc_k(const float* __restrict__ sw, const float* __restrict__ Cc,
           ushort* __restrict__ Wp)
{
    const int i = blockIdx.x >> 4;
    const int m = ((blockIdx.x & 15) << 4) + (threadIdx.x >> 4);
    const int s = threadIdx.x & 15;
    const float* swr = sw + ((size_t)i << 16) + (m << 8);
    const float* cc  = Cc + ((size_t)i << 12) + s;
    float acc = 0.0f;
    #pragma unroll 8
    for (int d = 0; d < 256; ++d) acc = fmaf(swr[d], cc[d << 4], acc);
    ushort* o = Wp + ((size_t)i << 14) + (m << 6);
    o[s] = f2b(acc);
    o[s + 16] = 0; o[s + 32] = 0; o[s + 48] = 0;
}

// mean over L (bf16 in, bf16 out): G[b,d] = mean_t X[b,t,d]
__global__ __launch_bounds__(256)
void meanL_k(const ushort* __restrict__ X, ushort* __restrict__ G)
{
    const int idx = blockIdx.x * 256 + threadIdx.x;
    const int b = idx >> 8, d = idx & 255;
    const ushort* xp = X + (size_t)b * (Lseq * Dm) + d;
    float s = 0.0f;
    #pragma unroll
    for (int t = 0; t < Lseq; ++t) s += b2f(xp[t << 8]);
    G[idx] = f2b(s * (1.0f / 32.0f));
}

__global__ __launch_bounds__(256)
void fillw_k(float* __restrict__ out)
{
    const int i = blockIdx.x * 256 + threadIdx.x;
    const float wm = 1.0f / 32.0f;
    out[i] = wm / (wm + wm + 1e-6f);
}

__global__ __launch_bounds__(256)
void cast_k(const float* __restrict__ src, ushort* __restrict__ dst, int n4)
{
    const int i = blockIdx.x * 256 + threadIdx.x;
    if (i < n4) {
        const float4 v = reinterpret_cast<const float4*>(src)[i];
        ushort4 o; o.x = f2b(v.x); o.y = f2b(v.y); o.z = f2b(v.z); o.w = f2b(v.w);
        reinterpret_cast<ushort4*>(dst)[i] = o;
    }
}

__global__ __launch_bounds__(256)
void cast_inw_k(const float* __restrict__ src, ushort* __restrict__ dst)
{
    const int i = blockIdx.x * 256 + threadIdx.x;
    const int blk = i >> 14, rem = i & 16383;
    const float4 v = reinterpret_cast<const float4*>(
        src + (size_t)blk * 131072 + 65536)[rem];
    ushort4 o; o.x = f2b(v.x); o.y = f2b(v.y); o.z = f2b(v.z); o.w = f2b(v.w);
    reinterpret_cast<ushort4*>(dst)[i] = o;
}

extern "C" void kernel_launch(void* const* d_in, const int* in_sizes, int n_in,
                              void* d_out, int out_size, void* d_ws, size_t ws_size,
                              hipStream_t stream)
{
    const float* ble_f   = (const float*)d_in[0];
    const float* vis_f   = (const float*)d_in[1];
    const float* bp_w    = (const float*)d_in[2];
    const float* bp_b    = (const float*)d_in[3];
    const float* bp_emb  = (const float*)d_in[4];
    const float* bp_g    = (const float*)d_in[5];
    const float* bp_beta = (const float*)d_in[6];
    const float* vp_w    = (const float*)d_in[7];
    const float* vp_b    = (const float*)d_in[8];
    const float* vp_emb  = (const float*)d_in[9];
    const float* vp_g    = (const float*)d_in[10];
    const float* vp_beta = (const float*)d_in[11];
    const float* a_qw    = (const float*)d_in[12];
    const float* a_qb    = (const float*)d_in[13];
    const float* a_kw    = (const float*)d_in[14];
    const float* a_kb    = (const float*)d_in[15];
    const float* a_vw    = (const float*)d_in[16];
    const float* a_vb    = (const float*)d_in[17];
    const float* a_ow    = (const float*)d_in[18];
    const float* a_ob    = (const float*)d_in[19];
    const float* a_g     = (const float*)d_in[20];
    const float* a_beta  = (const float*)d_in[21];
    const float* m_ln1_g = (const float*)d_in[22];
    const float* m_ln1_b = (const float*)d_in[23];
    const float* m_in_w  = (const float*)d_in[24];
    const float* m_in_b  = (const float*)d_in[25];
    const float* m_A     = (const float*)d_in[26];
    const float* m_B     = (const float*)d_in[27];
    const float* m_C     = (const float*)d_in[28];
    const float* m_gw    = (const float*)d_in[29];
    const float* m_gb    = (const float*)d_in[30];
    const float* m_sw    = (const float*)d_in[31];
    const float* m_sb    = (const float*)d_in[32];
    const float* m_ln2_g = (const float*)d_in[33];
    const float* m_ln2_b = (const float*)d_in[34];
    const float* m_f1w   = (const float*)d_in[35];
    const float* m_f1b   = (const float*)d_in[36];
    const float* m_f2w   = (const float*)d_in[37];
    const float* m_f2b   = (const float*)d_in[38];
    const float* fin_g   = (const float*)d_in[39];
    const float* fin_beta= (const float*)d_in[40];
    const float* fin_w   = (const float*)d_in[41];
    const float* fin_b   = (const float*)d_in[42];

    float* out = (float*)d_out;
    float* ws  = (float*)d_ws;
    const size_t NDf = (size_t)NROW * Dm;

    ushort* F_res = (ushort*)ws;             // bf16 residual stream
    ushort* Gpool = F_res + NDf;
    float*  F2    = ws + 3 * NDf;            // overlay arena only
    ushort* S0 = (ushort*)(ws + 4 * NDf);
    ushort* S1 = S0 + NDf;
    ushort* S2 = S1 + NDf;
    ushort* S3 = S2 + NDf;
    ushort* S4 = S3 + NDf;
    ushort* Wa = S4 + NDf;
    ushort* W_bp  = Wa;
    ushort* W_vp  = W_bp + 32768;
    ushort* W_q   = W_vp + 65536;
    ushort* W_k   = W_q + 131072;
    ushort* W_v   = W_k + 131072;
    ushort* W_o   = W_v + 131072;
    ushort* W_g   = W_o + 131072;
    ushort* W_in  = W_g + 393216;
    ushort* W_f1  = W_in + 393216;
    ushort* W_f2  = W_f1 + 1572864;
    ushort* W_fin = W_f2 + 1572864;
    ushort* W_sc  = W_fin + 65536;          // 6 * 256*64 (stride 64)
    ushort* Hpad  = W_sc + 98304;           // 32768*64 (stride 64)
    ushort* B_ble = (ushort*)F2;
    ushort* B_vis = B_ble + (size_t)NROW * 128;
    ushort* T_all = (ushort*)F2;
    ushort* W_bm  = T_all + 1572864;
    ushort* XBuf  = W_bm + 24576;

    const dim3 blk(256);
    auto cgrid = [](int n4) { return dim3((n4 + 255) / 256); };

    cast_k<<<cgrid(1048576), blk, 0, stream>>>(ble_f, B_ble, 1048576);
    cast_k<<<cgrid(2097152), blk, 0, stream>>>(vis_f, B_vis, 2097152);
    cast_k<<<cgrid(8192),   blk, 0, stream>>>(bp_w, W_bp, 8192);
    cast_k<<<cgrid(16384),  blk, 0, stream>>>(vp_w, W_vp, 16384);
    cast_k<<<cgrid(32768),  blk, 0, stream>>>(a_qw, W_q, 32768);
    cast_k<<<cgrid(32768),  blk, 0, stream>>>(a_kw, W_k, 32768);
    cast_k<<<cgrid(32768),  blk, 0, stream>>>(a_vw, W_v, 32768);
    cast_k<<<cgrid(32768),  blk, 0, stream>>>(a_ow, W_o, 32768);
    cast_k<<<cgrid(98304),  blk, 0, stream>>>(m_gw, W_g, 98304);
    cast_k<<<cgrid(393216), blk, 0, stream>>>(m_f1w, W_f1, 393216);
    cast_k<<<cgrid(393216), blk, 0, stream>>>(m_f2w, W_f2, 393216);
    cast_k<<<cgrid(16384),  blk, 0, stream>>>(fin_w, W_fin, 16384);
    cast_inw_k<<<cgrid(98304), blk, 0, stream>>>(m_in_w, W_in);
    wsc_k<<<96, blk, 0, stream>>>(m_sw, m_C, W_sc);

    auto gg = [](int M, int N) { return dim3(M / 128, N / 128); };
    const dim3 gRow(NROW / 32);

    // ---- input projections + fused LN (bf16 LN out only) ----
    growln_k<false,false,false,1,true><<<gRow, blk, 0, stream>>>(
        B_ble, W_bp, bp_b, bp_emb, nullptr, bp_g, bp_beta, nullptr, S0, 128);
    growln_k<false,false,false,1,true><<<gRow, blk, 0, stream>>>(
        B_vis, W_vp, vp_b, vp_emb, nullptr, vp_g, vp_beta, nullptr, S1, 256);

    // ---- two cross-attentions (residual from bf16 S0/S1) ----
    for (int a = 0; a < 2; ++a) {
        const ushort* qin_b = (a == 0) ? S0 : S1;
        const ushort* kin_b = (a == 0) ? S1 : S0;
        const size_t wo = (size_t)a * 65536;
        const size_t bo = (size_t)a * 256;
        mgemm<0,true,0,0><<<gg(256, NROW), blk, 0, stream>>>(
            qin_b, W_q + wo, nullptr, a_qb + bo, nullptr, nullptr, S4, nullptr, 256, 256);
        mgemm<0,true,0,2><<<gg(256, NROW), blk, 0, stream>>>(
            kin_b, W_k + wo, W_v + wo, a_kb + bo, a_vb + bo, nullptr, S2, S3, 256, 256);
        attn_k<<<Bsz * 8, blk, 0, stream>>>(S4, S2, S3, S4);
        if (a == 0)
            growln_k<true,false,false,2,false><<<gRow, blk, 0, stream>>>(
                S4, W_o + wo, a_ob + bo, nullptr, qin_b, a_g + bo, a_beta + bo, F_res, nullptr, 256);
        else
            growln_k<true,false,false,4,false><<<gRow, blk, 0, stream>>>(
                S4, W_o + wo, a_ob + bo, nullptr, qin_b, a_g + bo, a_beta + bo, F_res, nullptr, 256);
    }

    // ---- scan matrices (overlay F2, now dead) ----
    powT_k<<<6, blk, 0, stream>>>(m_A, T_all);
    cast_k<<<cgrid(6144), blk, 0, stream>>>(m_B, W_bm, 6144);
    zeroH_k<<<1024, blk, 0, stream>>>(Hpad);

    // ln1 of block 0
    ln_k<<<NROW/4, blk, 0, stream>>>(F_res, m_ln1_g, m_ln1_b, S0);

    // ---- 6 mamba blocks ----
    for (int i = 0; i < 6; ++i) {
        mgemm<0,true,0,1><<<gg(256, NROW), blk, 0, stream>>>(
            S0, W_g + (size_t)i*65536, W_in + (size_t)i*65536,
            m_gb + i*256, m_in_b + (size_t)i*512 + 256, nullptr, S2, nullptr, 256, 256);
        xb_gemm<<<NROW/128, blk, 0, stream>>>(S2, W_bm + (size_t)i*4096, XBuf);
        mgemm<0,true,1,0><<<gg(512, 1024), blk, 0, stream>>>(
            XBuf, T_all + (size_t)i*262144, nullptr, nullptr, nullptr, nullptr, Hpad, nullptr, 512, 512);
        // F_res += H@(sw@C)^T + sb (bf16 residual); S0 = ln2(F_res). K=64 (padded)
        growln_k<false,true,true,1,false><<<gRow, blk, 0, stream>>>(
            Hpad, W_sc + (size_t)i*16384, m_sb + i*256, nullptr, nullptr,
            m_ln2_g + i*256, m_ln2_b + i*256, F_res, S0, 64);
        // S1 = gelu(S0 @ W1^T + b1)  — proven 128^2 mgemm
        mgemm<2,true,0,0><<<gg(1024, NROW), blk, 0, stream>>>(
            S0, W_f1 + (size_t)i*262144, nullptr, m_f1b + i*1024, nullptr, nullptr, S1, nullptr, 256, 1024);
        if (i < 5)
            growln_k<false,true,true,1,false><<<gRow, blk, 0, stream>>>(
                S1, W_f2 + (size_t)i*262144, m_f2b + i*256, nullptr, nullptr,
                m_ln1_g + (i+1)*256, m_ln1_b + (i+1)*256, F_res, S0, 1024);
        else
            growln_k<false,true,true,0,false><<<gRow, blk, 0, stream>>>(
                S1, W_f2 + (size_t)i*262144, m_f2b + i*256, nullptr, nullptr,
                nullptr, nullptr, F_res, nullptr, 1024);
    }

    // ---- head ----
    meanL_k<<<(Bsz * Dm) / 256, blk, 0, stream>>>(F_res, Gpool);
    ln_k<<<Bsz/4, blk, 0, stream>>>(Gpool, fin_g, fin_beta, S1);
    mgemm<2,false,0,0><<<gg(256, Bsz), blk, 0, stream>>>(
        S1, W_fin, nullptr, fin_b, nullptr, out, nullptr, nullptr, 256, 256);
    fillw_k<<<8, blk, 0, stream>>>(out + (size_t)Bsz * Dm);
}

// Round 15
// 1078.197 us; speedup vs baseline: 1.0545x; 1.0175x over previous
//
#include <hip/hip_runtime.h>
#include <hip/hip_bf16.h>
#include <math.h>

static constexpr int Bsz  = 1024;
static constexpr int Lseq = 32;
static constexpr int Dm   = 256;
static constexpr int NROW = Bsz * Lseq;   // 32768

typedef __attribute__((ext_vector_type(8))) short bf16x8;
typedef __attribute__((ext_vector_type(4))) float f32x4;

__device__ __forceinline__ float sigm_f(float x) {
    return 1.0f / (1.0f + __expf(-x));
}
__device__ __forceinline__ float gelu_f(float x) {
    const float u = x * (0.7978845608028654f + 0.0356774081f * x * x);
    return x * sigm_f(2.0f * u);
}
__device__ __forceinline__ float b2f(ushort u) {
    union { float f; uint v; } t; t.v = ((uint)u) << 16; return t.f;
}
__device__ __forceinline__ ushort f2b(float f) {
    union { float f; uint v; } t; t.f = f;
    const uint lsb = (t.v >> 16) & 1u;
    t.v += 0x7fffu + lsb;
    return (ushort)(t.v >> 16);
}

#define GLDS(gp, lp) __builtin_amdgcn_global_load_lds( \
    (const __attribute__((address_space(1))) void*)(gp), \
    (__attribute__((address_space(3))) void*)(lp), 16, 0, 0)

// BK=64 staging scheme: chunk = 8 rows x 64 cols bf16 (1 KB);
// lane l -> row l>>3, 16B-slot l&7; stored slot = s ^ (row & 7).
// LDS ushort idx (row r, k-slot s): r*64 + ((s ^ (r&7)) << 3).

// ---------------------------------------------------------------------------
// bf16 MFMA GEMM, 128x128 tile, BK=64, 256 threads (proven version).
// ACT: 0 none, 1 sigm, 2 gelu. OMAP: 1 = scan-H remap (stride-64 Hpad) with
// triangular K-limit. DUAL: 1 gateIn; 2 two outputs.
// XCD-aware bijective block swizzle + LDS-repacked coalesced bf16 epilogue.
// ---------------------------------------------------------------------------
template<int ACT, bool OUTBF, int OMAP, int DUAL>
__global__ __launch_bounds__(256)
void mgemm(const ushort* __restrict__ X, const ushort* __restrict__ W,
           const ushort* __restrict__ W2,
           const float* __restrict__ b1, const float* __restrict__ b2,
           float* __restrict__ Cf, ushort* __restrict__ Cb,
           ushort* __restrict__ Cb2, int K, int M)
{
    __shared__ ushort As[8192];                 // 128 x 64
    __shared__ ushort Bs[8192];
    __shared__ ushort Bs2[DUAL ? 8192 : 8];
    const int tid = threadIdx.x;
    const int w = tid >> 6, l = tid & 63;

    int f = blockIdx.y * gridDim.x + blockIdx.x;
    const int nwg = gridDim.x * gridDim.y;
    if ((nwg & 7) == 0) f = (f & 7) * (nwg >> 3) + (f >> 3);
    const int n0 = (f / gridDim.x) << 7;
    const int m0 = (f % gridDim.x) << 7;

    const int ric = l >> 3;          // row in chunk 0..7
    const int sl  = l & 7;           // 16B slot 0..7
    const ushort* gAp[4]; const ushort* gBp[4]; const ushort* gCp[DUAL ? 4 : 1];
    ushort* lAp[4]; ushort* lBp[4]; ushort* lCp[DUAL ? 4 : 1];
    #pragma unroll
    for (int c = 0; c < 4; ++c) {
        const int r = ((w << 2) + c) * 8 + ric;
        const int eo = (sl ^ (r & 7)) << 3;
        gAp[c] = X + (size_t)(n0 + r) * K + eo;
        gBp[c] = W + (size_t)(m0 + r) * K + eo;
        lAp[c] = As + (((w << 2) + c) << 9);
        lBp[c] = Bs + (((w << 2) + c) << 9);
        if constexpr (DUAL) {
            gCp[c] = W2 + (size_t)(m0 + r) * K + eo;
            lCp[c] = Bs2 + (((w << 2) + c) << 9);
        }
    }

    const int wr = (w >> 1) & 1, wc = w & 1;
    const int cl = l & 15, kg = l >> 4;
    int aoff[2][4], boff[2][4];
    #pragma unroll
    for (int sub = 0; sub < 2; ++sub) {
        const int s = sub * 4 + kg;
        #pragma unroll
        for (int m = 0; m < 4; ++m) {
            const int r = wr * 64 + m * 16 + cl;
            aoff[sub][m] = r * 64 + ((s ^ (r & 7)) << 3);
        }
        #pragma unroll
        for (int n = 0; n < 4; ++n) {
            const int r = wc * 64 + n * 16 + cl;
            boff[sub][n] = r * 64 + ((s ^ (r & 7)) << 3);
        }
    }

    f32x4 acc[4][4];
    f32x4 acc2[DUAL ? 4 : 1][DUAL ? 4 : 1];
    #pragma unroll
    for (int m = 0; m < 4; ++m)
        #pragma unroll
        for (int n = 0; n < 4; ++n) {
            acc[m][n] = (f32x4){0.f, 0.f, 0.f, 0.f};
            if constexpr (DUAL) acc2[m][n] = (f32x4){0.f, 0.f, 0.f, 0.f};
        }

    const int Klim = (OMAP == 1) ? (m0 + 128 < K ? m0 + 128 : K) : K;
    for (int kc = 0; kc < Klim; kc += 64) {
        #pragma unroll
        for (int c = 0; c < 4; ++c) {
            GLDS(gAp[c], lAp[c]); gAp[c] += 64;
            GLDS(gBp[c], lBp[c]); gBp[c] += 64;
            if constexpr (DUAL) { GLDS(gCp[c], lCp[c]); gCp[c] += 64; }
        }
        __syncthreads();
        #pragma unroll
        for (int sub = 0; sub < 2; ++sub) {
            bf16x8 av[4], bv[4];
            #pragma unroll
            for (int m = 0; m < 4; ++m) av[m] = *(const bf16x8*)(As + aoff[sub][m]);
            #pragma unroll
            for (int n = 0; n < 4; ++n) bv[n] = *(const bf16x8*)(Bs + boff[sub][n]);
            #pragma unroll
            for (int m = 0; m < 4; ++m)
                #pragma unroll
                for (int n = 0; n < 4; ++n)
                    acc[m][n] = __builtin_amdgcn_mfma_f32_16x16x32_bf16(
                        av[m], bv[n], acc[m][n], 0, 0, 0);
            if constexpr (DUAL) {
                bf16x8 cv[4];
                #pragma unroll
                for (int n = 0; n < 4; ++n) cv[n] = *(const bf16x8*)(Bs2 + boff[sub][n]);
                #pragma unroll
                for (int m = 0; m < 4; ++m)
                    #pragma unroll
                    for (int n = 0; n < 4; ++n)
                        acc2[m][n] = __builtin_amdgcn_mfma_f32_16x16x32_bf16(
                            av[m], cv[n], acc2[m][n], 0, 0, 0);
            }
        }
        __syncthreads();
    }

    const int colb = m0 + wc * 64 + cl;
    const int rowb = n0 + wr * 64 + (kg << 2);
    float biasA[4], biasB[4];
    #pragma unroll
    for (int n = 0; n < 4; ++n) {
        biasA[n] = (b1 != nullptr) ? b1[colb + n * 16] : 0.0f;
        if constexpr (DUAL) biasB[n] = b2[colb + n * 16];
    }

    if constexpr (OUTBF || DUAL != 0) {
        ushort* Rw = (w == 0) ? As : (w == 1) ? As + 4096
                   : (w == 2) ? Bs : Bs + 4096;
        const int rr = l >> 3, rc8 = (l & 7) << 3;
        const int nout = (DUAL == 2) ? 2 : 1;
        for (int which = 0; which < nout; ++which) {
            #pragma unroll
            for (int m = 0; m < 4; ++m)
                #pragma unroll
                for (int j = 0; j < 4; ++j) {
                    const int lrow = m * 16 + (kg << 2) + j;
                    #pragma unroll
                    for (int n = 0; n < 4; ++n) {
                        float v;
                        if (which == 0) {
                            v = acc[m][n][j] + biasA[n];
                            if constexpr (DUAL == 1)
                                v = sigm_f(v) * (acc2[m][n][j] + biasB[n]);
                            else if (ACT == 1) v = sigm_f(v);
                            else if (ACT == 2) v = gelu_f(v);
                        } else {
                            v = acc2[m][n][j] + biasB[n];
                        }
                        const int lcol = (n << 4) + cl;
                        Rw[lrow * 64 + (lcol ^ (((lrow >> 1) & 7) << 3))] = f2b(v);
                    }
                }
            ushort* dst = (which == 0) ? Cb : Cb2;
            #pragma unroll
            for (int p = 0; p < 8; ++p) {
                const int lrow = (p << 3) + rr;
                const bf16x8 v8 = *(const bf16x8*)(
                    Rw + lrow * 64 + (rc8 ^ (((lrow >> 1) & 7) << 3)));
                const size_t grow = (size_t)(n0 + wr * 64 + lrow);
                const int gcol = m0 + wc * 64 + rc8;
                size_t idx;
                if (OMAP == 1) idx = grow * 2048 + ((size_t)(gcol >> 4) << 6) + (gcol & 15);
                else           idx = grow * (size_t)M + gcol;
                *(bf16x8*)(dst + idx) = v8;
            }
        }
    } else {
        #pragma unroll
        for (int m = 0; m < 4; ++m)
            #pragma unroll
            for (int j = 0; j < 4; ++j) {
                const size_t row = (size_t)(rowb + m * 16 + j);
                #pragma unroll
                for (int n = 0; n < 4; ++n) {
                    float v = acc[m][n][j] + biasA[n];
                    if (ACT == 1) v = sigm_f(v);
                    else if (ACT == 2) v = gelu_f(v);
                    Cf[row * (size_t)M + colb + n * 16] = v;
                }
            }
    }
}

// ---------------------------------------------------------------------------
// Full-row GEMM + fused residual/LN, col-split, BK=64, bf16 residual stream.
// ---------------------------------------------------------------------------
template<bool ADD_E, bool ACC_F, bool WRV, int LNOUT, bool HASB2>
__global__ __launch_bounds__(256)
void growln_k(const ushort* __restrict__ X, const ushort* __restrict__ W,
              const float* __restrict__ b1, const float* __restrict__ b2,
              const ushort* __restrict__ E, const float* __restrict__ g,
              const float* __restrict__ bt, ushort* __restrict__ Fres,
              ushort* __restrict__ Yb, int K)
{
    __shared__ ushort As[32 * 64];     // 4 KB
    __shared__ ushort Bs[256 * 64];    // 32 KB
    __shared__ float sred[32][2];
    __shared__ float qred[32][2];
    const int tid = threadIdx.x;
    const int w = tid >> 6, l = tid & 63;
    const int n0 = blockIdx.x << 5;
    const int rowg = w >> 1, colg = w & 1;

    const int ric = l >> 3, sl = l & 7;
    const ushort* gB[8]; ushort* lB[8];
    #pragma unroll
    for (int c = 0; c < 8; ++c) {
        const int rB = ((w << 3) + c) * 8 + ric;
        gB[c] = W + (size_t)rB * K + ((sl ^ (rB & 7)) << 3);
        lB[c] = Bs + (((w << 3) + c) << 9);
    }
    const int rA = (w << 3) + ric;
    const ushort* gA = X + (size_t)(n0 + rA) * K + ((sl ^ (rA & 7)) << 3);
    ushort* lA = As + (w << 9);

    const int cl = l & 15, kg = l >> 4;
    const int ar = rowg * 16 + cl;
    int aoff[2], boff[2][8];
    #pragma unroll
    for (int sub = 0; sub < 2; ++sub) {
        const int s = sub * 4 + kg;
        aoff[sub] = ar * 64 + ((s ^ (ar & 7)) << 3);
        #pragma unroll
        for (int n = 0; n < 8; ++n) {
            const int br = colg * 128 + n * 16 + cl;
            boff[sub][n] = br * 64 + ((s ^ (br & 7)) << 3);
        }
    }

    f32x4 acc[8];
    #pragma unroll
    for (int n = 0; n < 8; ++n) acc[n] = (f32x4){0.f, 0.f, 0.f, 0.f};

    for (int kc = 0; kc < K; kc += 64) {
        #pragma unroll
        for (int c = 0; c < 8; ++c) { GLDS(gB[c], lB[c]); gB[c] += 64; }
        GLDS(gA, lA); gA += 64;
        __syncthreads();
        #pragma unroll
        for (int sub = 0; sub < 2; ++sub) {
            const bf16x8 av = *(const bf16x8*)(As + aoff[sub]);
            #pragma unroll
            for (int n = 0; n < 8; ++n) {
                const bf16x8 bv = *(const bf16x8*)(Bs + boff[sub][n]);
                acc[n] = __builtin_amdgcn_mfma_f32_16x16x32_bf16(av, bv, acc[n], 0, 0, 0);
            }
        }
        __syncthreads();
    }

    float bA[8];
    #pragma unroll
    for (int n = 0; n < 8; ++n) {
        const int col = colg * 128 + n * 16 + cl;
        float v = (b1 != nullptr) ? b1[col] : 0.0f;
        if (HASB2) v += b2[col];
        bA[n] = v;
    }
    float gg[8], bb[8];
    if (LNOUT > 0) {
        #pragma unroll
        for (int n = 0; n < 8; ++n) {
            const int col = colg * 128 + n * 16 + cl;
            gg[n] = g[col]; bb[n] = bt[col];
        }
    }

    #pragma unroll
    for (int j = 0; j < 4; ++j) {
        const int lrow = rowg * 16 + (kg << 2) + j;
        const size_t rb = (size_t)(n0 + lrow) << 8;
        float s = 0.0f;
        #pragma unroll
        for (int n = 0; n < 8; ++n) {
            const size_t idx = rb + colg * 128 + n * 16 + cl;
            float x = acc[n][j] + bA[n];
            if (ADD_E) x += b2f(E[idx]);
            if (ACC_F) x += b2f(Fres[idx]);
            acc[n][j] = x; s += x;
        }
        if (WRV) {
            #pragma unroll
            for (int n = 0; n < 8; ++n)
                Fres[rb + colg * 128 + n * 16 + cl] = f2b(acc[n][j]);
        }
        if (LNOUT > 0) {
            #pragma unroll
            for (int o = 1; o < 16; o <<= 1) s += __shfl_xor(s, o);
            if (cl == 0) sred[lrow][colg] = s;
        }
    }
    if (LNOUT > 0) {
        __syncthreads();
        float mu[4];
        #pragma unroll
        for (int j = 0; j < 4; ++j) {
            const int lrow = rowg * 16 + (kg << 2) + j;
            mu[j] = (sred[lrow][0] + sred[lrow][1]) * (1.0f / 256.0f);
            float q = 0.0f;
            #pragma unroll
            for (int n = 0; n < 8; ++n) { const float d = acc[n][j] - mu[j]; q += d * d; }
            #pragma unroll
            for (int o = 1; o < 16; o <<= 1) q += __shfl_xor(q, o);
            if (cl == 0) qred[lrow][colg] = q;
        }
        __syncthreads();
        #pragma unroll
        for (int j = 0; j < 4; ++j) {
            const int lrow = rowg * 16 + (kg << 2) + j;
            const size_t rb = (size_t)(n0 + lrow) << 8;
            const float rstd = rsqrtf((qred[lrow][0] + qred[lrow][1]) * (1.0f / 256.0f) + 1e-5f);
            #pragma unroll
            for (int n = 0; n < 8; ++n) {
                const float y = (acc[n][j] - mu[j]) * rstd * gg[n] + bb[n];
                const size_t idx = rb + colg * 128 + n * 16 + cl;
                if (LNOUT & 1) Yb[idx] = f2b(y);
                if (LNOUT == 2 || LNOUT == 3) Fres[idx] = f2b(y);
                if (LNOUT == 4) Fres[idx] = f2b(b2f(Fres[idx]) + y);
            }
        }
    }
}

// ---------------------------------------------------------------------------
// Row LayerNorm (standalone), BF16 input. One wave/row, 4 rows/block.
// ---------------------------------------------------------------------------
__global__ __launch_bounds__(256)
void ln_k(const ushort* __restrict__ X, const float* __restrict__ g,
          const float* __restrict__ bt, ushort* __restrict__ Yb)
{
    const int lane = threadIdx.x & 63;
    const int row  = (blockIdx.x << 2) + (threadIdx.x >> 6);
    const size_t base = (size_t)row * Dm + (lane << 2);
    const ushort4 u = *reinterpret_cast<const ushort4*>(&X[base]);
    const float v0 = b2f(u.x), v1 = b2f(u.y), v2 = b2f(u.z), v3 = b2f(u.w);
    float s = v0 + v1 + v2 + v3;
    #pragma unroll
    for (int o = 1; o < 64; o <<= 1) s += __shfl_xor(s, o);
    const float mu = s * (1.0f / 256.0f);
    const float d0 = v0 - mu, d1 = v1 - mu, d2 = v2 - mu, d3 = v3 - mu;
    float q = d0*d0 + d1*d1 + d2*d2 + d3*d3;
    #pragma unroll
    for (int o = 1; o < 64; o <<= 1) q += __shfl_xor(q, o);
    const float rstd = rsqrtf(q * (1.0f / 256.0f) + 1e-5f);
    const int c = lane << 2;
    const float4 gg = *reinterpret_cast<const float4*>(&g[c]);
    const float4 bb = *reinterpret_cast<const float4*>(&bt[c]);
    ushort4 ub;
    ub.x = f2b(d0*rstd*gg.x + bb.x); ub.y = f2b(d1*rstd*gg.y + bb.y);
    ub.z = f2b(d2*rstd*gg.z + bb.z); ub.w = f2b(d3*rstd*gg.w + bb.w);
    *reinterpret_cast<ushort4*>(&Yb[base]) = ub;
}

// ---------------------------------------------------------------------------
// Fused head: G[b,:] = LN(mean_t F[b,t,:]) -> bf16. One block per batch row.
// ---------------------------------------------------------------------------
__global__ __launch_bounds__(256)
void poolln_k(const ushort* __restrict__ X, const float* __restrict__ g,
              const float* __restrict__ bt, ushort* __restrict__ Yb)
{
    __shared__ float red1[4], red2[4];
    const int b = blockIdx.x, d = threadIdx.x;
    const int wv = d >> 6;
    const ushort* xp = X + (size_t)b * (Lseq * Dm) + d;
    float s = 0.0f;
    #pragma unroll
    for (int t = 0; t < Lseq; ++t) s += b2f(xp[t << 8]);
    const float v = s * (1.0f / 32.0f);
    float ts = v;
    #pragma unroll
    for (int o = 1; o < 64; o <<= 1) ts += __shfl_xor(ts, o);
    if ((d & 63) == 0) red1[wv] = ts;
    __syncthreads();
    const float mu = (red1[0] + red1[1] + red1[2] + red1[3]) * (1.0f / 256.0f);
    float dq = (v - mu) * (v - mu);
    #pragma unroll
    for (int o = 1; o < 64; o <<= 1) dq += __shfl_xor(dq, o);
    if ((d & 63) == 0) red2[wv] = dq;
    __syncthreads();
    const float rstd = rsqrtf((red2[0] + red2[1] + red2[2] + red2[3]) * (1.0f / 256.0f) + 1e-5f);
    Yb[b * 256 + d] = f2b((v - mu) * rstd * g[d] + bt[d]);
}

// ---------------------------------------------------------------------------
// Cross-attention core, bf16 in/out, fp32 math. One (b,h) per block.
// ---------------------------------------------------------------------------
__global__ __launch_bounds__(256)
void attn_k(const ushort* __restrict__ Q, const ushort* __restrict__ K,
            const ushort* __restrict__ V, ushort* __restrict__ O)
{
    __shared__ float Qs[32][33], Ks[32][33], Vs[32][33], Ss[32][33];
    const int bh = blockIdx.x;
    const int b = bh >> 3, h = bh & 7;
    const int tid = threadIdx.x;
    const int r  = tid >> 3;
    const int c4 = (tid & 7) << 2;
    const size_t base = ((size_t)b * Lseq + r) * Dm + h * 32 + c4;
    {
        const ushort4 q = *reinterpret_cast<const ushort4*>(&Q[base]);
        Qs[r][c4+0]=b2f(q.x); Qs[r][c4+1]=b2f(q.y); Qs[r][c4+2]=b2f(q.z); Qs[r][c4+3]=b2f(q.w);
        const ushort4 k = *reinterpret_cast<const ushort4*>(&K[base]);
        Ks[r][c4+0]=b2f(k.x); Ks[r][c4+1]=b2f(k.y); Ks[r][c4+2]=b2f(k.z); Ks[r][c4+3]=b2f(k.w);
        const ushort4 v = *reinterpret_cast<const ushort4*>(&V[base]);
        Vs[r][c4+0]=b2f(v.x); Vs[r][c4+1]=b2f(v.y); Vs[r][c4+2]=b2f(v.z); Vs[r][c4+3]=b2f(v.w);
    }
    __syncthreads();
    float sc[4] = {0.f, 0.f, 0.f, 0.f};
    #pragma unroll
    for (int d = 0; d < 32; ++d) {
        const float qv = Qs[r][d];
        #pragma unroll
        for (int j = 0; j < 4; ++j) sc[j] = fmaf(qv, Ks[c4+j][d], sc[j]);
    }
    #pragma unroll
    for (int j = 0; j < 4; ++j) sc[j] *= 0.17677669529663687f;
    float mx = fmaxf(fmaxf(sc[0], sc[1]), fmaxf(sc[2], sc[3]));
    #pragma unroll
    for (int o = 1; o < 8; o <<= 1) mx = fmaxf(mx, __shfl_xor(mx, o));
    float sum = 0.f;
    #pragma unroll
    for (int j = 0; j < 4; ++j) { sc[j] = __expf(sc[j] - mx); sum += sc[j]; }
    #pragma unroll
    for (int o = 1; o < 8; o <<= 1) sum += __shfl_xor(sum, o);
    const float inv = 1.0f / sum;
    #pragma unroll
    for (int j = 0; j < 4; ++j) Ss[r][c4+j] = sc[j] * inv;
    __syncthreads();
    float o4[4] = {0.f, 0.f, 0.f, 0.f};
    #pragma unroll
    for (int k = 0; k < 32; ++k) {
        const float wv = Ss[r][k];
        #pragma unroll
        for (int j = 0; j < 4; ++j) o4[j] = fmaf(wv, Vs[k][c4+j], o4[j]);
    }
    ushort4 ob; ob.x=f2b(o4[0]); ob.y=f2b(o4[1]); ob.z=f2b(o4[2]); ob.w=f2b(o4[3]);
    *reinterpret_cast<ushort4*>(&O[base]) = ob;
}

// ---------------------------------------------------------------------------
// XB GEMM: XB[n,s] = sum_d X[n,d] * Bw[s,d]   (N x 16, K=256, bf16 out)
// ---------------------------------------------------------------------------
__global__ __launch_bounds__(256)
void xb_gemm(const ushort* __restrict__ X, const ushort* __restrict__ Bw,
             ushort* __restrict__ XB)
{
    __shared__ ushort As[128 * 32];
    __shared__ ushort Bsf[16 * 256];
    const int tid = threadIdx.x;
    const int w = tid >> 6, l = tid & 63;
    const int n0 = blockIdx.x << 7;
    #pragma unroll
    for (int rep = 0; rep < 2; ++rep) {
        const int u = (rep << 8) + tid;
        const int r = u >> 5;
        const int c8 = (u & 31) << 3;
        const int di = (r * 256 + c8) ^ ((r & 7) << 3);
        *(bf16x8*)(Bsf + di) = *(const bf16x8*)(Bw + r * 256 + c8);
    }
    const int ric = l >> 2, slot = l & 3;
    const int rL0 = (w << 4) + ric, rL1 = rL0 + 64;
    const int sw0 = slot ^ ((rL0 >> 1) & 3), sw1 = slot ^ ((rL1 >> 1) & 3);
    const ushort* gA0 = X + (size_t)(n0 + rL0) * 256 + (sw0 << 3);
    const ushort* gA1 = X + (size_t)(n0 + rL1) * 256 + (sw1 << 3);
    ushort* lA0 = As + (w << 9);
    ushort* lA1 = As + ((w + 4) << 9);
    const int cl = l & 15, kg = l >> 4;
    int aoff[2];
    #pragma unroll
    for (int m = 0; m < 2; ++m) {
        const int r = w * 32 + m * 16 + cl;
        aoff[m] = r * 32 + ((kg ^ ((r >> 1) & 3)) << 3);
    }
    f32x4 acc[2] = {(f32x4){0.f,0.f,0.f,0.f}, (f32x4){0.f,0.f,0.f,0.f}};
    for (int kc = 0; kc < 256; kc += 32) {
        GLDS(gA0, lA0); GLDS(gA1, lA1);
        gA0 += 32; gA1 += 32;
        __syncthreads();
        const bf16x8 av0 = *(const bf16x8*)(As + aoff[0]);
        const bf16x8 av1 = *(const bf16x8*)(As + aoff[1]);
        const int bidx = (cl * 256 + kc + (kg << 3)) ^ ((cl & 7) << 3);
        const bf16x8 bv = *(const bf16x8*)(Bsf + bidx);
        acc[0] = __builtin_amdgcn_mfma_f32_16x16x32_bf16(av0, bv, acc[0], 0, 0, 0);
        acc[1] = __builtin_amdgcn_mfma_f32_16x16x32_bf16(av1, bv, acc[1], 0, 0, 0);
        __syncthreads();
    }
    #pragma unroll
    for (int m = 0; m < 2; ++m)
        #pragma unroll
        for (int j = 0; j < 4; ++j) {
            const int row = n0 + w * 32 + m * 16 + (kg << 2) + j;
            XB[(size_t)row * 16 + cl] = f2b(acc[m][j]);
        }
}

// ---------------------------------------------------------------------------
// powT: T[t*16+s'][tau*16+s] = (A^(t-tau))[s'][s] for t>=tau else 0.
// ---------------------------------------------------------------------------
__global__ __launch_bounds__(256)
void powT_k(const float* __restrict__ A_all, ushort* __restrict__ T_all)
{
    __shared__ float P[2][16][16];
    __shared__ float Asm[16][16];
    const int layer = blockIdx.x;
    const float* A = A_all + layer * 256;
    ushort* T = T_all + (size_t)layer * 262144;
    const int tid = threadIdx.x;
    const int i = tid >> 4, j = tid & 15;
    Asm[i][j] = A[tid];
    const bf16x8 z = {0,0,0,0,0,0,0,0};
    for (int u = tid; u < 32768; u += 256)
        *(bf16x8*)(T + (size_t)u * 8) = z;
    P[0][i][j] = (i == j) ? 1.0f : 0.0f;
    __syncthreads();
    for (int k = 0; k < 32; ++k) {
        const float pv = P[k & 1][i][j];
        const ushort pb = f2b(pv);
        for (int tau = 0; tau + k < 32; ++tau)
            T[(size_t)((tau + k) * 16 + i) * 512 + tau * 16 + j] = pb;
        float acc = 0.0f;
        #pragma unroll
        for (int l2 = 0; l2 < 16; ++l2) acc = fmaf(P[k & 1][i][l2], Asm[l2][j], acc);
        P[(k & 1) ^ 1][i][j] = acc;
        __syncthreads();
    }
}

// zero Hpad (32768 x 64 bf16)
__global__ __launch_bounds__(256)
void zeroH_k(ushort* __restrict__ Hp)
{
    const int i = blockIdx.x * 256 + threadIdx.x;
    const bf16x8 z = {0,0,0,0,0,0,0,0};
    *(bf16x8*)(Hp + (size_t)i * 8) = z;
}

// W_scpad[i][m][s] (stride 64): s<16 = sum_d sw*C, s in [16,64) = 0
__global__ __launch_bounds__(256)
void wsc_k(const float* __restrict__ sw, const float* __restrict__ Cc,
           ushort* __restrict__ Wp)
{
    const int i = blockIdx.x >> 4;
    const int m = ((blockIdx.x & 15) << 4) + (threadIdx.x >> 4);
    const int s = threadIdx.x & 15;
    const float* swr = sw + ((size_t)i << 16) + (m << 8);
    const float* cc  = Cc + ((size_t)i << 12) + s;
    float acc = 0.0f;
    #pragma unroll 8
    for (int d = 0; d < 256; ++d) acc = fmaf(swr[d], cc[d << 4], acc);
    ushort* o = Wp + ((size_t)i << 14) + (m << 6);
    o[s] = f2b(acc);
    o[s + 16] = 0; o[s + 32] = 0; o[s + 48] = 0;
}

__global__ __launch_bounds__(256)
void fillw_k(float* __restrict__ out)
{
    const int i = blockIdx.x * 256 + threadIdx.x;
    const float wm = 1.0f / 32.0f;
    out[i] = wm / (wm + wm + 1e-6f);
}

// ---------------------------------------------------------------------------
// Batched fp32->bf16 cast of ALL weights/inputs in ONE launch.
// Segment boundaries in float4 units (compile-time constants).
// Segment 12 = m_in_w strided extraction (rows 256..511 of each 512x256 blk).
// ---------------------------------------------------------------------------
__global__ __launch_bounds__(256)
void castall_k(const float* __restrict__ s0, ushort* __restrict__ d0,   // ble 1048576
               const float* __restrict__ s1, ushort* __restrict__ d1,   // vis 2097152
               const float* __restrict__ s2, ushort* __restrict__ d2,   // bp 8192
               const float* __restrict__ s3, ushort* __restrict__ d3,   // vp 16384
               const float* __restrict__ s4, ushort* __restrict__ d4,   // qw 32768
               const float* __restrict__ s5, ushort* __restrict__ d5,   // kw 32768
               const float* __restrict__ s6, ushort* __restrict__ d6,   // vw 32768
               const float* __restrict__ s7, ushort* __restrict__ d7,   // ow 32768
               const float* __restrict__ s8, ushort* __restrict__ d8,   // gw 98304
               const float* __restrict__ s9, ushort* __restrict__ d9,   // f1w 393216
               const float* __restrict__ s10, ushort* __restrict__ d10, // f2w 393216
               const float* __restrict__ s11, ushort* __restrict__ d11, // fin 16384
               const float* __restrict__ s12, ushort* __restrict__ d12) // inw 98304
{
    const int i = blockIdx.x * 256 + threadIdx.x;   // float4 index, < 4300800
    const float* src; ushort* dst; int loc; bool strided = false;
    if      (i < 1048576) { src = s0;  dst = d0;  loc = i; }
    else if (i < 3145728) { src = s1;  dst = d1;  loc = i - 1048576; }
    else if (i < 3153920) { src = s2;  dst = d2;  loc = i - 3145728; }
    else if (i < 3170304) { src = s3;  dst = d3;  loc = i - 3153920; }
    else if (i < 3203072) { src = s4;  dst = d4;  loc = i - 3170304; }
    else if (i < 3235840) { src = s5;  dst = d5;  loc = i - 3203072; }
    else if (i < 3268608) { src = s6;  dst = d6;  loc = i - 3235840; }
    else if (i < 3301376) { src = s7;  dst = d7;  loc = i - 3268608; }
    else if (i < 3399680) { src = s8;  dst = d8;  loc = i - 3301376; }
    else if (i < 3792896) { src = s9;  dst = d9;  loc = i - 3399680; }
    else if (i < 4186112) { src = s10; dst = d10; loc = i - 3792896; }
    else if (i < 4202496) { src = s11; dst = d11; loc = i - 4186112; }
    else                  { src = s12; dst = d12; loc = i - 4202496; strided = true; }
    float4 v;
    if (strided) {
        const int blk = loc >> 14, rem = loc & 16383;
        v = reinterpret_cast<const float4*>(src + (size_t)blk * 131072 + 65536)[rem];
    } else {
        v = reinterpret_cast<const float4*>(src)[loc];
    }
    ushort4 o; o.x = f2b(v.x); o.y = f2b(v.y); o.z = f2b(v.z); o.w = f2b(v.w);
    reinterpret_cast<ushort4*>(dst)[loc] = o;
}

extern "C" void kernel_launch(void* const* d_in, const int* in_sizes, int n_in,
                              void* d_out, int out_size, void* d_ws, size_t ws_size,
                              hipStream_t stream)
{
    const float* ble_f   = (const float*)d_in[0];
    const float* vis_f   = (const float*)d_in[1];
    const float* bp_w    = (const float*)d_in[2];
    const float* bp_b    = (const float*)d_in[3];
    const float* bp_emb  = (const float*)d_in[4];
    const float* bp_g    = (const float*)d_in[5];
    const float* bp_beta = (const float*)d_in[6];
    const float* vp_w    = (const float*)d_in[7];
    const float* vp_b    = (const float*)d_in[8];
    const float* vp_emb  = (const float*)d_in[9];
    const float* vp_g    = (const float*)d_in[10];
    const float* vp_beta = (const float*)d_in[11];
    const float* a_qw    = (const float*)d_in[12];
    const float* a_qb    = (const float*)d_in[13];
    const float* a_kw    = (const float*)d_in[14];
    const float* a_kb    = (const float*)d_in[15];
    const float* a_vw    = (const float*)d_in[16];
    const float* a_vb    = (const float*)d_in[17];
    const float* a_ow    = (const float*)d_in[18];
    const float* a_ob    = (const float*)d_in[19];
    const float* a_g     = (const float*)d_in[20];
    const float* a_beta  = (const float*)d_in[21];
    const float* m_ln1_g = (const float*)d_in[22];
    const float* m_ln1_b = (const float*)d_in[23];
    const float* m_in_w  = (const float*)d_in[24];
    const float* m_in_b  = (const float*)d_in[25];
    const float* m_A     = (const float*)d_in[26];
    const float* m_B     = (const float*)d_in[27];
    const float* m_C     = (const float*)d_in[28];
    const float* m_gw    = (const float*)d_in[29];
    const float* m_gb    = (const float*)d_in[30];
    const float* m_sw    = (const float*)d_in[31];
    const float* m_sb    = (const float*)d_in[32];
    const float* m_ln2_g = (const float*)d_in[33];
    const float* m_ln2_b = (const float*)d_in[34];
    const float* m_f1w   = (const float*)d_in[35];
    const float* m_f1b   = (const float*)d_in[36];
    const float* m_f2w   = (const float*)d_in[37];
    const float* m_f2b   = (const float*)d_in[38];
    const float* fin_g   = (const float*)d_in[39];
    const float* fin_beta= (const float*)d_in[40];
    const float* fin_w   = (const float*)d_in[41];
    const float* fin_b   = (const float*)d_in[42];

    float* out = (float*)d_out;
    float* ws  = (float*)d_ws;
    const size_t NDf = (size_t)NROW * Dm;

    ushort* F_res = (ushort*)ws;             // bf16 residual stream
    ushort* Gpool = F_res + NDf;
    float*  F2    = ws + 3 * NDf;            // overlay arena only
    ushort* S0 = (ushort*)(ws + 4 * NDf);
    ushort* S1 = S0 + NDf;
    ushort* S2 = S1 + NDf;
    ushort* S3 = S2 + NDf;
    ushort* S4 = S3 + NDf;
    ushort* Wa = S4 + NDf;
    ushort* W_bp  = Wa;
    ushort* W_vp  = W_bp + 32768;
    ushort* W_q   = W_vp + 65536;
    ushort* W_k   = W_q + 131072;
    ushort* W_v   = W_k + 131072;
    ushort* W_o   = W_v + 131072;
    ushort* W_g   = W_o + 131072;
    ushort* W_in  = W_g + 393216;
    ushort* W_f1  = W_in + 393216;
    ushort* W_f2  = W_f1 + 1572864;
    ushort* W_fin = W_f2 + 1572864;
    ushort* W_sc  = W_fin + 65536;          // 6 * 256*64 (stride 64)
    ushort* Hpad  = W_sc + 98304;           // 32768*64 (stride 64)
    ushort* B_ble = (ushort*)F2;
    ushort* B_vis = B_ble + (size_t)NROW * 128;
    ushort* T_all = (ushort*)F2;
    ushort* W_bm  = T_all + 1572864;
    ushort* XBuf  = W_bm + 24576;

    const dim3 blk(256);
    auto cgrid = [](int n4) { return dim3((n4 + 255) / 256); };

    // ---- single-launch weight/input casts + folds ----
    castall_k<<<16800, blk, 0, stream>>>(
        ble_f, B_ble, vis_f, B_vis, bp_w, W_bp, vp_w, W_vp,
        a_qw, W_q, a_kw, W_k, a_vw, W_v, a_ow, W_o,
        m_gw, W_g, m_f1w, W_f1, m_f2w, W_f2, fin_w, W_fin,
        m_in_w, W_in);
    wsc_k<<<96, blk, 0, stream>>>(m_sw, m_C, W_sc);

    auto gg = [](int M, int N) { return dim3(M / 128, N / 128); };
    const dim3 gRow(NROW / 32);

    // ---- input projections + fused LN (bf16 LN out only) ----
    growln_k<false,false,false,1,true><<<gRow, blk, 0, stream>>>(
        B_ble, W_bp, bp_b, bp_emb, nullptr, bp_g, bp_beta, nullptr, S0, 128);
    growln_k<false,false,false,1,true><<<gRow, blk, 0, stream>>>(
        B_vis, W_vp, vp_b, vp_emb, nullptr, vp_g, vp_beta, nullptr, S1, 256);

    // ---- two cross-attentions (residual from bf16 S0/S1) ----
    for (int a = 0; a < 2; ++a) {
        const ushort* qin_b = (a == 0) ? S0 : S1;
        const ushort* kin_b = (a == 0) ? S1 : S0;
        const size_t wo = (size_t)a * 65536;
        const size_t bo = (size_t)a * 256;
        mgemm<0,true,0,0><<<gg(256, NROW), blk, 0, stream>>>(
            qin_b, W_q + wo, nullptr, a_qb + bo, nullptr, nullptr, S4, nullptr, 256, 256);
        mgemm<0,true,0,2><<<gg(256, NROW), blk, 0, stream>>>(
            kin_b, W_k + wo, W_v + wo, a_kb + bo, a_vb + bo, nullptr, S2, S3, 256, 256);
        attn_k<<<Bsz * 8, blk, 0, stream>>>(S4, S2, S3, S4);
        if (a == 0)
            growln_k<true,false,false,2,false><<<gRow, blk, 0, stream>>>(
                S4, W_o + wo, a_ob + bo, nullptr, qin_b, a_g + bo, a_beta + bo, F_res, nullptr, 256);
        else
            growln_k<true,false,false,4,false><<<gRow, blk, 0, stream>>>(
                S4, W_o + wo, a_ob + bo, nullptr, qin_b, a_g + bo, a_beta + bo, F_res, nullptr, 256);
    }

    // ---- scan matrices (overlay F2, now dead) ----
    powT_k<<<6, blk, 0, stream>>>(m_A, T_all);
    cast_kernel_bm:
    {
        // small m_B cast folded into a tiny launch (6144 float4)
    }
    // m_B cast (24576 floats): reuse castall? separate tiny launch kept simple:
    // (uses fillw-style simple cast below)
    {
        // inline simple cast for m_B
    }
    // Use a dedicated small cast for W_bm (6144 float4s):
    // reusing zeroH grid-compatible simple kernel below.
    // (launch after powT)
    // m_B -> W_bm
    // NOTE: implemented via lambda-less direct launch:
    extern __global__ void castbm_k(const float*, ushort*);
    castbm_k<<<24, blk, 0, stream>>>(m_B, W_bm);
    zeroH_k<<<1024, blk, 0, stream>>>(Hpad);

    // ln1 of block 0
    ln_k<<<NROW/4, blk, 0, stream>>>(F_res, m_ln1_g, m_ln1_b, S0);

    // ---- 6 mamba blocks ----
    for (int i = 0; i < 6; ++i) {
        mgemm<0,true,0,1><<<gg(256, NROW), blk, 0, stream>>>(
            S0, W_g + (size_t)i*65536, W_in + (size_t)i*65536,
            m_gb + i*256, m_in_b + (size_t)i*512 + 256, nullptr, S2, nullptr, 256, 256);
        xb_gemm<<<NROW/128, blk, 0, stream>>>(S2, W_bm + (size_t)i*4096, XBuf);
        mgemm<0,true,1,0><<<gg(512, 1024), blk, 0, stream>>>(
            XBuf, T_all + (size_t)i*262144, nullptr, nullptr, nullptr, nullptr, Hpad, nullptr, 512, 512);
        growln_k<false,true,true,1,false><<<gRow, blk, 0, stream>>>(
            Hpad, W_sc + (size_t)i*16384, m_sb + i*256, nullptr, nullptr,
            m_ln2_g + i*256, m_ln2_b + i*256, F_res, S0, 64);
        mgemm<2,true,0,0><<<gg(1024, NROW), blk, 0, stream>>>(
            S0, W_f1 + (size_t)i*262144, nullptr, m_f1b + i*1024, nullptr, nullptr, S1, nullptr, 256, 1024);
        if (i < 5)
            growln_k<false,true,true,1,false><<<gRow, blk, 0, stream>>>(
                S1, W_f2 + (size_t)i*262144, m_f2b + i*256, nullptr, nullptr,
                m_ln1_g + (i+1)*256, m_ln1_b + (i+1)*256, F_res, S0, 1024);
        else
            growln_k<false,true,true,0,false><<<gRow, blk, 0, stream>>>(
                S1, W_f2 + (size_t)i*262144, m_f2b + i*256, nullptr, nullptr,
                nullptr, nullptr, F_res, nullptr, 1024);
    }

    // ---- head (fused pool+LN) ----
    poolln_k<<<Bsz, blk, 0, stream>>>(F_res, fin_g, fin_beta, S1);
    mgemm<2,false,0,0><<<gg(256, Bsz), blk, 0, stream>>>(
        S1, W_fin, nullptr, fin_b, nullptr, out, nullptr, nullptr, 256, 256);
    fillw_k<<<8, blk, 0, stream>>>(out + (size_t)Bsz * Dm);
}

// m_B cast: 6*16*256 floats = 6144 float4
__global__ __launch_bounds__(256)
void castbm_k(const float* __restrict__ src, ushort* __restrict__ dst)
{
    const int i = blockIdx.x * 256 + threadIdx.x;   // < 6144
    if (i < 6144) {
        const float4 v = reinterpret_cast<const float4*>(src)[i];
        ushort4 o; o.x = f2b(v.x); o.y = f2b(v.y); o.z = f2b(v.z); o.w = f2b(v.w);
        reinterpret_cast<ushort4*>(dst)[i] = o;
    }
}